// Round 1
// baseline (3867.024 us; speedup 1.0000x reference)
//
#include <hip/hip_runtime.h>
#include <math.h>

#define NA 30000
#define NB 100000
#define NHALF 50000
#define NANG 200000
#define DD 128
#define HH 256
#define LL 8
#define RPB 16

// ---------------- node init: node[r][c] = sum_i atom_emb[i][cat[r][i]][c]
__global__ __launch_bounds__(256) void k_node_init(
    const int* __restrict__ cat, const float* __restrict__ emb,
    float* __restrict__ node)
{
    int tid = threadIdx.x;
    int r = blockIdx.x * 2 + (tid >> 7);
    int c = tid & 127;
    const int* cr = cat + r * 9;
    float v = 0.f;
    #pragma unroll
    for (int i = 0; i < 9; ++i) v += emb[((i << 6) + cr[i]) * DD + c];
    node[(size_t)r * DD + c] = v;
}

// ---------------- layer-0 ab scatter with fused edge build
__global__ __launch_bounds__(256) void k_scatter_ab_init(
    const float* __restrict__ node,
    const int* __restrict__ bcat, const float* __restrict__ bfloat,
    const float* __restrict__ emb,   // (3,16,128)
    const float* __restrict__ rw,    // (20,128)
    const float* __restrict__ rbv,   // (128)
    const int* __restrict__ src, const int* __restrict__ dst,
    float* __restrict__ agg)
{
    __shared__ float sR[2][20];
    int tid = threadIdx.x;
    int sub = tid >> 7, c = tid & 127;
    int e = blockIdx.x * 2 + sub;
    if (c < 20) {
        float d = bfloat[e] - 0.1f * (float)c;
        sR[sub][c] = expf(-10.f * d * d);
    }
    __syncthreads();
    float v = rbv[c];
    #pragma unroll
    for (int k = 0; k < 20; ++k) v += sR[sub][k] * rw[k * DD + c];
    const int* bc = bcat + e * 3;
    #pragma unroll
    for (int j = 0; j < 3; ++j) v += emb[((j << 4) + bc[j]) * DD + c];
    v += node[(size_t)src[e] * DD + c];
    atomicAdd(&agg[(size_t)dst[e] * DD + c], v);
}

// ---------------- ab scatter, layers >=1: edge[e] = half[e>>1]
__global__ __launch_bounds__(256) void k_scatter_ab(
    const float* __restrict__ node, const float* __restrict__ half,
    const int* __restrict__ src, const int* __restrict__ dst,
    float* __restrict__ agg)
{
    int tid = threadIdx.x;
    int e = blockIdx.x * 2 + (tid >> 7);
    int c = tid & 127;
    float v = node[(size_t)src[e] * DD + c] + half[(size_t)(e >> 1) * DD + c];
    atomicAdd(&agg[(size_t)dst[e] * DD + c], v);
}

// ---------------- per-layer bond_embed for even bonds (rows of half-graph)
__global__ __launch_bounds__(256) void k_bond_embed(
    const int* __restrict__ bcat, const float* __restrict__ bfloat,
    const float* __restrict__ emb, const float* __restrict__ rw,
    const float* __restrict__ rbv, float* __restrict__ out)
{
    __shared__ float sR[2][20];
    int tid = threadIdx.x;
    int sub = tid >> 7, c = tid & 127;
    int i = blockIdx.x * 2 + sub;
    int e = i * 2;
    if (c < 20) {
        float d = bfloat[e] - 0.1f * (float)c;
        sR[sub][c] = expf(-10.f * d * d);
    }
    __syncthreads();
    float v = rbv[c];
    #pragma unroll
    for (int k = 0; k < 20; ++k) v += sR[sub][k] * rw[k * DD + c];
    const int* bc = bcat + e * 3;
    #pragma unroll
    for (int j = 0; j < 3; ++j) v += emb[((j << 4) + bc[j]) * DD + c];
    out[(size_t)i * DD + c] = v;
}

// ---------------- ba scatter with fused angle RBF (K=32)
__global__ __launch_bounds__(256) void k_scatter_ba(
    const float* __restrict__ bemb, const float* __restrict__ afloat,
    const float* __restrict__ rw, const float* __restrict__ rbv,
    const int* __restrict__ src, const int* __restrict__ dst,
    float* __restrict__ agg)
{
    __shared__ float sR[2][32];
    int tid = threadIdx.x;
    int sub = tid >> 7, c = tid & 127;
    int e = blockIdx.x * 2 + sub;
    if (c < 32) {
        float d = afloat[e] - 0.1f * (float)c;
        sR[sub][c] = expf(-10.f * d * d);
    }
    __syncthreads();
    float v = rbv[c];
    #pragma unroll
    for (int k = 0; k < 32; ++k) v += sR[sub][k] * rw[k * DD + c];
    v += bemb[(size_t)src[e] * DD + c];
    atomicAdd(&agg[(size_t)dst[e] * DD + c], v);
}

// ---------------- fused MLP (128->256 relu ->128) + LN + /sqrt(n) + relu + residual
// 16 rows per block, 256 threads. In-place out==node_in is safe (each element
// read once then written by the same thread).
__global__ __launch_bounds__(256) void k_mlp(
    const float* __restrict__ agg, const float* __restrict__ node_in,
    const float* __restrict__ w1, const float* __restrict__ b1,
    const float* __restrict__ w2, const float* __restrict__ b2,
    const float* __restrict__ g, const float* __restrict__ bt,
    float* __restrict__ out, float inv_sqrt_n)
{
    __shared__ float sA[RPB][DD];   // A tile, reused as LN staging
    __shared__ float sH[RPB][HH];   // hidden
    const int tid = threadIdx.x;
    const size_t row0 = (size_t)blockIdx.x * RPB;

    {   // load 16x128 A tile (2048 floats, 8/thread as 2 float4)
        const float4* s4 = (const float4*)(agg + row0 * DD);
        float4* d4 = (float4*)&sA[0][0];
        d4[tid] = s4[tid];
        d4[tid + 256] = s4[tid + 256];
    }
    __syncthreads();

    {   // phase 1: hidden col j = tid, all 16 rows
        float acc[RPB];
        #pragma unroll
        for (int r = 0; r < RPB; ++r) acc[r] = 0.f;
        const float* w1c = w1 + tid;
        for (int k = 0; k < DD; k += 4) {
            float wa = w1c[(k + 0) * HH];
            float wb = w1c[(k + 1) * HH];
            float wc = w1c[(k + 2) * HH];
            float wd = w1c[(k + 3) * HH];
            #pragma unroll
            for (int r = 0; r < RPB; ++r) {
                float4 a4 = *(const float4*)&sA[r][k];
                acc[r] += a4.x * wa + a4.y * wb + a4.z * wc + a4.w * wd;
            }
        }
        float bb = b1[tid];
        #pragma unroll
        for (int r = 0; r < RPB; ++r) sH[r][tid] = fmaxf(acc[r] + bb, 0.f);
    }
    __syncthreads();

    // phase 2: out col ci, 8 rows per thread
    const int ci = tid & 127;
    const int rb = (tid >> 7) * 8;
    {
        float o[8];
        #pragma unroll
        for (int r = 0; r < 8; ++r) o[r] = 0.f;
        const float* w2c = w2 + ci;
        for (int k = 0; k < HH; k += 4) {
            float wa = w2c[(k + 0) * DD];
            float wb = w2c[(k + 1) * DD];
            float wc = w2c[(k + 2) * DD];
            float wd = w2c[(k + 3) * DD];
            #pragma unroll
            for (int r = 0; r < 8; ++r) {
                float4 h4 = *(const float4*)&sH[rb + r][k];
                o[r] += h4.x * wa + h4.y * wb + h4.z * wc + h4.w * wd;
            }
        }
        float bb = b2[ci];
        #pragma unroll
        for (int r = 0; r < 8; ++r) sA[rb + r][ci] = o[r] + bb;
    }
    __syncthreads();

    // phase 3: LN + scale + relu + residual. wave w handles rows 4w..4w+3.
    const int wave = tid >> 6, lane = tid & 63;
    float gl0 = g[lane], gl1 = g[lane + 64];
    float bl0 = bt[lane], bl1 = bt[lane + 64];
    #pragma unroll
    for (int rr = 0; rr < 4; ++rr) {
        int r = wave * 4 + rr;
        float x0 = sA[r][lane], x1 = sA[r][lane + 64];
        float s = x0 + x1, ss = x0 * x0 + x1 * x1;
        #pragma unroll
        for (int off = 32; off > 0; off >>= 1) {
            s  += __shfl_down(s, off);
            ss += __shfl_down(ss, off);
        }
        s = __shfl(s, 0); ss = __shfl(ss, 0);
        float mu  = s * (1.f / 128.f);
        float var = ss * (1.f / 128.f) - mu * mu;
        float rstd = rsqrtf(var + 1e-5f);
        size_t base = (row0 + r) * DD;
        float y0 = (x0 - mu) * rstd * gl0 + bl0;
        float y1 = (x1 - mu) * rstd * gl1 + bl1;
        y0 = fmaxf(y0 * inv_sqrt_n, 0.f) + node_in[base + lane];
        y1 = fmaxf(y1 * inv_sqrt_n, 0.f) + node_in[base + lane + 64];
        out[base + lane] = y0;
        out[base + lane + 64] = y1;
    }
}

// ---------------- final edge = repeat(half, 2)
__global__ __launch_bounds__(256) void k_expand_edge(
    const float4* __restrict__ half, float4* __restrict__ out)
{
    int t = blockIdx.x * 256 + threadIdx.x;   // over NB*32 float4s
    out[t] = half[((t >> 6) << 5) | (t & 31)];
}

// ---------------- graph = node.mean(axis=0)
__global__ __launch_bounds__(256) void k_graph_mean(
    const float* __restrict__ node, float* __restrict__ graph)
{
    int tid = threadIdx.x;
    int c = tid & 127, h = tid >> 7;
    const int rpb = 250;
    int r0 = blockIdx.x * rpb;
    float s = 0.f;
    for (int r = r0 + h; r < r0 + rpb; r += 2) s += node[(size_t)r * DD + c];
    __shared__ float sS[256];
    sS[tid] = s;
    __syncthreads();
    if (tid < 128) atomicAdd(&graph[c], (sS[tid] + sS[tid + 128]) * (1.f / 30000.f));
}

extern "C" void kernel_launch(void* const* d_in, const int* in_sizes, int n_in,
                              void* d_out, int out_size, void* d_ws, size_t ws_size,
                              hipStream_t stream)
{
    const int*   atom_cat         = (const int*)d_in[0];
    const int*   bond_cat         = (const int*)d_in[1];
    const float* bond_float       = (const float*)d_in[2];
    const float* angle_float      = (const float*)d_in[3];
    const int*   ab_src           = (const int*)d_in[4];
    const int*   ab_dst           = (const int*)d_in[5];
    const int*   ba_src           = (const int*)d_in[6];
    const int*   ba_dst           = (const int*)d_in[7];
    const float* atom_emb         = (const float*)d_in[8];
    const float* bond_emb_init    = (const float*)d_in[9];
    const float* bond_rbf_w_init  = (const float*)d_in[10];
    const float* bond_rbf_b_init  = (const float*)d_in[11];
    const float* layer_bond_emb   = (const float*)d_in[12];
    const float* layer_bond_rbf_w = (const float*)d_in[13];
    const float* layer_bond_rbf_b = (const float*)d_in[14];
    const float* layer_angle_rbf_w= (const float*)d_in[15];
    const float* layer_angle_rbf_b= (const float*)d_in[16];
    const float* ab_w1 = (const float*)d_in[17];
    const float* ab_b1 = (const float*)d_in[18];
    const float* ab_w2 = (const float*)d_in[19];
    const float* ab_b2 = (const float*)d_in[20];
    const float* ab_g  = (const float*)d_in[21];
    const float* ab_bt = (const float*)d_in[22];
    const float* ba_w1 = (const float*)d_in[23];
    const float* ba_b1 = (const float*)d_in[24];
    const float* ba_w2 = (const float*)d_in[25];
    const float* ba_b2 = (const float*)d_in[26];
    const float* ba_g  = (const float*)d_in[27];
    const float* ba_bt = (const float*)d_in[28];

    float* node     = (float*)d_out;                  // NA*DD (live node buffer)
    float* edge_out = node + (size_t)NA * DD;         // NB*DD
    float* graph    = edge_out + (size_t)NB * DD;     // DD

    // ws: agg (shared ab/ba lifetimes, NHALF*DD) | bemb | half  => 76.8 MB
    float* agg  = (float*)d_ws;
    float* bemb = agg  + (size_t)NHALF * DD;
    float* half = bemb + (size_t)NHALF * DD;

    const float isn_a = (float)(1.0 / sqrt(30000.0));
    const float isn_h = (float)(1.0 / sqrt(50000.0));

    k_node_init<<<NA / 2, 256, 0, stream>>>(atom_cat, atom_emb, node);

    for (int l = 0; l < LL; ++l) {
        hipMemsetAsync(agg, 0, (size_t)NA * DD * sizeof(float), stream);
        if (l == 0)
            k_scatter_ab_init<<<NB / 2, 256, 0, stream>>>(
                node, bond_cat, bond_float, bond_emb_init,
                bond_rbf_w_init, bond_rbf_b_init, ab_src, ab_dst, agg);
        else
            k_scatter_ab<<<NB / 2, 256, 0, stream>>>(node, half, ab_src, ab_dst, agg);

        k_mlp<<<NA / RPB, 256, 0, stream>>>(agg, node,
            ab_w1 + (size_t)l * DD * HH, ab_b1 + l * HH,
            ab_w2 + (size_t)l * HH * DD, ab_b2 + l * DD,
            ab_g + l * DD, ab_bt + l * DD, node, isn_a);

        k_bond_embed<<<NHALF / 2, 256, 0, stream>>>(bond_cat, bond_float,
            layer_bond_emb + (size_t)l * 3 * 16 * DD,
            layer_bond_rbf_w + (size_t)l * 20 * DD,
            layer_bond_rbf_b + l * DD, bemb);

        hipMemsetAsync(agg, 0, (size_t)NHALF * DD * sizeof(float), stream);
        k_scatter_ba<<<NANG / 2, 256, 0, stream>>>(bemb, angle_float,
            layer_angle_rbf_w + (size_t)l * 32 * DD,
            layer_angle_rbf_b + l * DD, ba_src, ba_dst, agg);

        k_mlp<<<NHALF / RPB, 256, 0, stream>>>(agg, bemb,
            ba_w1 + (size_t)l * DD * HH, ba_b1 + l * HH,
            ba_w2 + (size_t)l * HH * DD, ba_b2 + l * DD,
            ba_g + l * DD, ba_bt + l * DD, half, isn_h);
    }

    k_expand_edge<<<(NB * DD / 4) / 256, 256, 0, stream>>>(
        (const float4*)half, (float4*)edge_out);

    hipMemsetAsync(graph, 0, DD * sizeof(float), stream);
    k_graph_mean<<<120, 256, 0, stream>>>(node, graph);
}

// Round 2
// 2353.152 us; speedup vs baseline: 1.6433x; 1.6433x over previous
//
#include <hip/hip_runtime.h>
#include <math.h>

#define NA 30000
#define NB 100000
#define NHALF 50000
#define NANG 200000
#define DD 128
#define HH 256
#define LL 8
#define MT 64   // rows per MLP block

typedef unsigned short ushort_t;
typedef short s16x8 __attribute__((ext_vector_type(8)));
typedef float f32x4 __attribute__((ext_vector_type(4)));

__device__ __forceinline__ ushort_t f2bf(float x) {
    unsigned int u = __builtin_bit_cast(unsigned int, x);
    u += 0x7fff + ((u >> 16) & 1);
    return (ushort_t)(u >> 16);
}
__device__ __forceinline__ float bf2f(ushort_t b) {
    unsigned int u = ((unsigned int)b) << 16;
    return __builtin_bit_cast(float, u);
}

// ---------------- node init: node[r][c] = sum_i atom_emb[i][cat[r][i]][c]
__global__ __launch_bounds__(256) void k_node_init(
    const int* __restrict__ cat, const float* __restrict__ emb,
    float* __restrict__ node)
{
    int tid = threadIdx.x;
    int r = blockIdx.x * 2 + (tid >> 7);
    int c = tid & 127;
    const int* cr = cat + r * 9;
    float v = 0.f;
    #pragma unroll
    for (int i = 0; i < 9; ++i) v += emb[((i << 6) + cr[i]) * DD + c];
    node[(size_t)r * DD + c] = v;
}

// ---------------- layer-0 ab scatter with fused edge build
__global__ __launch_bounds__(256) void k_scatter_ab_init(
    const float* __restrict__ node,
    const int* __restrict__ bcat, const float* __restrict__ bfloat,
    const float* __restrict__ emb,   // (3,16,128)
    const float* __restrict__ rw,    // (20,128)
    const float* __restrict__ rbv,   // (128)
    const int* __restrict__ src, const int* __restrict__ dst,
    float* __restrict__ agg)
{
    __shared__ float sR[2][20];
    int tid = threadIdx.x;
    int sub = tid >> 7, c = tid & 127;
    int e = blockIdx.x * 2 + sub;
    if (c < 20) {
        float d = bfloat[e] - 0.1f * (float)c;
        sR[sub][c] = expf(-10.f * d * d);
    }
    __syncthreads();
    float v = rbv[c];
    #pragma unroll
    for (int k = 0; k < 20; ++k) v += sR[sub][k] * rw[k * DD + c];
    const int* bc = bcat + e * 3;
    #pragma unroll
    for (int j = 0; j < 3; ++j) v += emb[((j << 4) + bc[j]) * DD + c];
    v += node[(size_t)src[e] * DD + c];
    atomicAdd(&agg[(size_t)dst[e] * DD + c], v);
}

// ---------------- ab scatter, layers >=1: edge[e] = half[e>>1]
__global__ __launch_bounds__(256) void k_scatter_ab(
    const float* __restrict__ node, const float* __restrict__ half,
    const int* __restrict__ src, const int* __restrict__ dst,
    float* __restrict__ agg)
{
    int tid = threadIdx.x;
    int e = blockIdx.x * 2 + (tid >> 7);
    int c = tid & 127;
    float v = node[(size_t)src[e] * DD + c] + half[(size_t)(e >> 1) * DD + c];
    atomicAdd(&agg[(size_t)dst[e] * DD + c], v);
}

// ---------------- per-layer bond_embed for even bonds (bf16 out)
__global__ __launch_bounds__(256) void k_bond_embed(
    const int* __restrict__ bcat, const float* __restrict__ bfloat,
    const float* __restrict__ emb, const float* __restrict__ rw,
    const float* __restrict__ rbv, ushort_t* __restrict__ out)
{
    __shared__ float sR[2][20];
    int tid = threadIdx.x;
    int sub = tid >> 7, c = tid & 127;
    int i = blockIdx.x * 2 + sub;
    int e = i * 2;
    if (c < 20) {
        float d = bfloat[e] - 0.1f * (float)c;
        sR[sub][c] = expf(-10.f * d * d);
    }
    __syncthreads();
    float v = rbv[c];
    #pragma unroll
    for (int k = 0; k < 20; ++k) v += sR[sub][k] * rw[k * DD + c];
    const int* bc = bcat + e * 3;
    #pragma unroll
    for (int j = 0; j < 3; ++j) v += emb[((j << 4) + bc[j]) * DD + c];
    out[(size_t)i * DD + c] = f2bf(v);
}

// ---------------- ba scatter with fused angle RBF (K=32), bemb bf16
__global__ __launch_bounds__(256) void k_scatter_ba(
    const ushort_t* __restrict__ bemb, const float* __restrict__ afloat,
    const float* __restrict__ rw, const float* __restrict__ rbv,
    const int* __restrict__ src, const int* __restrict__ dst,
    float* __restrict__ agg)
{
    __shared__ float sR[2][32];
    int tid = threadIdx.x;
    int sub = tid >> 7, c = tid & 127;
    int e = blockIdx.x * 2 + sub;
    if (c < 32) {
        float d = afloat[e] - 0.1f * (float)c;
        sR[sub][c] = expf(-10.f * d * d);
    }
    __syncthreads();
    float v = rbv[c];
    #pragma unroll
    for (int k = 0; k < 32; ++k) v += sR[sub][k] * rw[k * DD + c];
    v += bf2f(bemb[(size_t)src[e] * DD + c]);
    atomicAdd(&agg[(size_t)dst[e] * DD + c], v);
}

// ---------------- weight packing into MFMA B-fragment order (bf16)
// frag index f: mat = f>>12 (mat = (g*8+l)*2 + m), fi = f&4095,
// lane = fi&63, ts = fi>>6; w1: t=ts>>2,s=ts&3,N=256; w2: t=ts>>3,s=ts&7,N=128
// out element = W[(s*32 + (lane>>4)*8 + j)*N + t*16 + (lane&15)]
__global__ __launch_bounds__(256) void k_pack_w(
    const float* __restrict__ ab_w1, const float* __restrict__ ab_w2,
    const float* __restrict__ ba_w1, const float* __restrict__ ba_w2,
    ushort_t* __restrict__ wp)
{
    int f = blockIdx.x * 256 + threadIdx.x;   // 131072 total
    int mat = f >> 12;
    int fi = f & 4095;
    int lane = fi & 63, ts = fi >> 6;
    int m = mat & 1, gl = mat >> 1;
    int l = gl & 7, gg = gl >> 3;
    const float* W;
    int N, s, t;
    if (m == 0) { W = (gg ? ba_w1 : ab_w1) + (size_t)l * 32768; N = 256; s = ts & 3; t = ts >> 2; }
    else        { W = (gg ? ba_w2 : ab_w2) + (size_t)l * 32768; N = 128; s = ts & 7; t = ts >> 3; }
    int k0 = s * 32 + (lane >> 4) * 8;
    int n = t * 16 + (lane & 15);
    ushort_t tmp[8];
    #pragma unroll
    for (int j = 0; j < 8; ++j) tmp[j] = f2bf(W[(size_t)(k0 + j) * N + n]);
    unsigned int pk[4];
    #pragma unroll
    for (int j = 0; j < 4; ++j) pk[j] = (unsigned int)tmp[2*j] | ((unsigned int)tmp[2*j+1] << 16);
    *(uint4*)(wp + (size_t)f * 8) = make_uint4(pk[0], pk[1], pk[2], pk[3]);
}

// ---------------- MFMA fused MLP + LN + scale + relu + residual
// 64 rows/block, 256 threads (4 waves, 16 rows each).
template<bool RES_BF16>
__global__ __launch_bounds__(256) void k_mlp_mfma(
    const float* __restrict__ agg, const void* __restrict__ node_in,
    const ushort_t* __restrict__ w1p, const float* __restrict__ b1,
    const ushort_t* __restrict__ w2p, const float* __restrict__ b2,
    const float* __restrict__ g, const float* __restrict__ bt,
    float* __restrict__ out, float inv_sqrt_n, int nrows)
{
    __shared__ __align__(16) ushort_t sA[MT][136];    // A tile bf16, padded (17408 B)
    __shared__ __align__(16) ushort_t sC1[MT][264];   // hidden bf16, padded (33792 B)
    __shared__ __align__(16) ushort_t sW[4096];       // weight chunk (8192 B)

    const int tid = threadIdx.x;
    const int wid = tid >> 6, lane = tid & 63;
    const int row0 = blockIdx.x * MT;

    // ---- Phase A: load agg tile fp32 -> bf16 into sA
    {
        const float4* a4 = (const float4*)agg;
        #pragma unroll
        for (int i = 0; i < 8; ++i) {
            int idx = tid + i * 256;          // float4 index in 64x32 tile
            int row = idx >> 5, c4 = idx & 31;
            int grow = row0 + row;
            float4 v = make_float4(0.f, 0.f, 0.f, 0.f);
            if (grow < nrows) v = a4[(size_t)grow * 32 + c4];
            unsigned int lo = (unsigned int)f2bf(v.x) | ((unsigned int)f2bf(v.y) << 16);
            unsigned int hi = (unsigned int)f2bf(v.z) | ((unsigned int)f2bf(v.w) << 16);
            *(uint2*)&sA[row][c4 * 4] = make_uint2(lo, hi);
        }
    }
    __syncthreads();

    // ---- load A fragments (4 k-steps) for this wave
    const int arow = wid * 16 + (lane & 15);
    const int acol = (lane >> 4) * 8;
    s16x8 af[4];
    #pragma unroll
    for (int s = 0; s < 4; ++s) af[s] = *(const s16x8*)&sA[arow][s * 32 + acol];

    // ---- GEMM1: hidden = relu(A @ W1 + b1), N=256 in 8 chunks of 32 cols
    for (int c = 0; c < 8; ++c) {
        const float4* srcw = (const float4*)(w1p + (c << 12));
        float4* dstw = (float4*)sW;
        dstw[tid] = srcw[tid];
        dstw[tid + 256] = srcw[tid + 256];
        __syncthreads();
        #pragma unroll
        for (int tl = 0; tl < 2; ++tl) {
            int t = c * 2 + tl;
            f32x4 acc = {0.f, 0.f, 0.f, 0.f};
            #pragma unroll
            for (int s = 0; s < 4; ++s) {
                s16x8 bf = *(const s16x8*)&sW[(((tl * 4 + s) << 6) | lane) << 3];
                acc = __builtin_amdgcn_mfma_f32_16x16x32_bf16(af[s], bf, acc, 0, 0, 0);
            }
            int n = t * 16 + (lane & 15);
            float b1v = b1[n];
            int r0 = wid * 16 + (lane >> 4) * 4;
            #pragma unroll
            for (int r = 0; r < 4; ++r)
                sC1[r0 + r][n] = f2bf(fmaxf(acc[r] + b1v, 0.f));
        }
        __syncthreads();
    }

    // ---- load A2 fragments (8 k-steps) from hidden
    s16x8 a2[8];
    #pragma unroll
    for (int s = 0; s < 8; ++s) a2[s] = *(const s16x8*)&sC1[arow][s * 32 + acol];

    // ---- GEMM2: C2 = H @ W2, N=128 in 8 chunks of 16 cols; keep in regs
    f32x4 c2[8];
    for (int t = 0; t < 8; ++t) {
        const float4* srcw = (const float4*)(w2p + (t << 12));
        float4* dstw = (float4*)sW;
        dstw[tid] = srcw[tid];
        dstw[tid + 256] = srcw[tid + 256];
        __syncthreads();
        f32x4 acc = {0.f, 0.f, 0.f, 0.f};
        #pragma unroll
        for (int s = 0; s < 8; ++s) {
            s16x8 bf = *(const s16x8*)&sW[((s << 6) | lane) << 3];
            acc = __builtin_amdgcn_mfma_f32_16x16x32_bf16(a2[s], bf, acc, 0, 0, 0);
        }
        c2[t] = acc;
        __syncthreads();
    }

    // ---- epilogue: +b2, LN over 128 cols, *g+bt, /sqrt(n), relu, +residual
    const int colb = lane & 15;
    float b2v[8], gv[8], btv[8];
    #pragma unroll
    for (int t = 0; t < 8; ++t) {
        int n = t * 16 + colb;
        b2v[t] = b2[n]; gv[t] = g[n]; btv[t] = bt[n];
    }
    #pragma unroll
    for (int t = 0; t < 8; ++t)
        #pragma unroll
        for (int r = 0; r < 4; ++r) c2[t][r] += b2v[t];

    #pragma unroll
    for (int r = 0; r < 4; ++r) {
        float s = 0.f, ss = 0.f;
        #pragma unroll
        for (int t = 0; t < 8; ++t) { float x = c2[t][r]; s += x; ss += x * x; }
        #pragma unroll
        for (int m = 1; m < 16; m <<= 1) {
            s  += __shfl_xor(s, m);
            ss += __shfl_xor(ss, m);
        }
        float mu = s * (1.f / 128.f);
        float var = ss * (1.f / 128.f) - mu * mu;
        float rstd = rsqrtf(var + 1e-5f);
        int grow = row0 + wid * 16 + (lane >> 4) * 4 + r;
        if (grow < nrows) {
            #pragma unroll
            for (int t = 0; t < 8; ++t) {
                int n = t * 16 + colb;
                float y = (c2[t][r] - mu) * rstd * gv[t] + btv[t];
                float res = RES_BF16
                    ? bf2f(((const ushort_t*)node_in)[(size_t)grow * DD + n])
                    : ((const float*)node_in)[(size_t)grow * DD + n];
                out[(size_t)grow * DD + n] = fmaxf(y * inv_sqrt_n, 0.f) + res;
            }
        }
    }
}

// ---------------- final edge = repeat(half, 2)
__global__ __launch_bounds__(256) void k_expand_edge(
    const float4* __restrict__ half, float4* __restrict__ out)
{
    int t = blockIdx.x * 256 + threadIdx.x;   // over NB*32 float4s
    out[t] = half[((t >> 6) << 5) | (t & 31)];
}

// ---------------- graph = node.mean(axis=0)
__global__ __launch_bounds__(256) void k_graph_mean(
    const float* __restrict__ node, float* __restrict__ graph)
{
    int tid = threadIdx.x;
    int c = tid & 127, h = tid >> 7;
    const int rpb = 250;
    int r0 = blockIdx.x * rpb;
    float s = 0.f;
    for (int r = r0 + h; r < r0 + rpb; r += 2) s += node[(size_t)r * DD + c];
    __shared__ float sS[256];
    sS[tid] = s;
    __syncthreads();
    if (tid < 128) atomicAdd(&graph[c], (sS[tid] + sS[tid + 128]) * (1.f / 30000.f));
}

extern "C" void kernel_launch(void* const* d_in, const int* in_sizes, int n_in,
                              void* d_out, int out_size, void* d_ws, size_t ws_size,
                              hipStream_t stream)
{
    const int*   atom_cat         = (const int*)d_in[0];
    const int*   bond_cat         = (const int*)d_in[1];
    const float* bond_float       = (const float*)d_in[2];
    const float* angle_float      = (const float*)d_in[3];
    const int*   ab_src           = (const int*)d_in[4];
    const int*   ab_dst           = (const int*)d_in[5];
    const int*   ba_src           = (const int*)d_in[6];
    const int*   ba_dst           = (const int*)d_in[7];
    const float* atom_emb         = (const float*)d_in[8];
    const float* bond_emb_init    = (const float*)d_in[9];
    const float* bond_rbf_w_init  = (const float*)d_in[10];
    const float* bond_rbf_b_init  = (const float*)d_in[11];
    const float* layer_bond_emb   = (const float*)d_in[12];
    const float* layer_bond_rbf_w = (const float*)d_in[13];
    const float* layer_bond_rbf_b = (const float*)d_in[14];
    const float* layer_angle_rbf_w= (const float*)d_in[15];
    const float* layer_angle_rbf_b= (const float*)d_in[16];
    const float* ab_w1 = (const float*)d_in[17];
    const float* ab_b1 = (const float*)d_in[18];
    const float* ab_w2 = (const float*)d_in[19];
    const float* ab_b2 = (const float*)d_in[20];
    const float* ab_g  = (const float*)d_in[21];
    const float* ab_bt = (const float*)d_in[22];
    const float* ba_w1 = (const float*)d_in[23];
    const float* ba_b1 = (const float*)d_in[24];
    const float* ba_w2 = (const float*)d_in[25];
    const float* ba_b2 = (const float*)d_in[26];
    const float* ba_g  = (const float*)d_in[27];
    const float* ba_bt = (const float*)d_in[28];

    float* node     = (float*)d_out;                  // NA*DD (live node buffer)
    float* edge_out = node + (size_t)NA * DD;         // NB*DD
    float* graph    = edge_out + (size_t)NB * DD;     // DD

    // ws layout: agg fp32 (NHALF*DD) | half fp32 (NHALF*DD) | bemb bf16 | wpack bf16
    float*    agg   = (float*)d_ws;
    float*    half  = agg + (size_t)NHALF * DD;
    ushort_t* bemb  = (ushort_t*)(half + (size_t)NHALF * DD);
    ushort_t* wpack = bemb + (size_t)NHALF * DD;      // 2*8*65536 ushorts = 2 MB

    const float isn_a = (float)(1.0 / sqrt(30000.0));
    const float isn_h = (float)(1.0 / sqrt(50000.0));

    k_pack_w<<<512, 256, 0, stream>>>(ab_w1, ab_w2, ba_w1, ba_w2, wpack);
    k_node_init<<<NA / 2, 256, 0, stream>>>(atom_cat, atom_emb, node);

    for (int l = 0; l < LL; ++l) {
        const ushort_t* ab_w1p = wpack + (size_t)(0 * 8 + l) * 65536;
        const ushort_t* ab_w2p = ab_w1p + 32768;
        const ushort_t* ba_w1p = wpack + (size_t)(1 * 8 + l) * 65536;
        const ushort_t* ba_w2p = ba_w1p + 32768;

        hipMemsetAsync(agg, 0, (size_t)NA * DD * sizeof(float), stream);
        if (l == 0)
            k_scatter_ab_init<<<NB / 2, 256, 0, stream>>>(
                node, bond_cat, bond_float, bond_emb_init,
                bond_rbf_w_init, bond_rbf_b_init, ab_src, ab_dst, agg);
        else
            k_scatter_ab<<<NB / 2, 256, 0, stream>>>(node, half, ab_src, ab_dst, agg);

        k_mlp_mfma<false><<<(NA + MT - 1) / MT, 256, 0, stream>>>(
            agg, node, ab_w1p, ab_b1 + l * HH, ab_w2p, ab_b2 + l * DD,
            ab_g + l * DD, ab_bt + l * DD, node, isn_a, NA);

        k_bond_embed<<<NHALF / 2, 256, 0, stream>>>(bond_cat, bond_float,
            layer_bond_emb + (size_t)l * 3 * 16 * DD,
            layer_bond_rbf_w + (size_t)l * 20 * DD,
            layer_bond_rbf_b + l * DD, bemb);

        hipMemsetAsync(agg, 0, (size_t)NHALF * DD * sizeof(float), stream);
        k_scatter_ba<<<NANG / 2, 256, 0, stream>>>(bemb, angle_float,
            layer_angle_rbf_w + (size_t)l * 32 * DD,
            layer_angle_rbf_b + l * DD, ba_src, ba_dst, agg);

        k_mlp_mfma<true><<<(NHALF + MT - 1) / MT, 256, 0, stream>>>(
            agg, bemb, ba_w1p, ba_b1 + l * HH, ba_w2p, ba_b2 + l * DD,
            ba_g + l * DD, ba_bt + l * DD, half, isn_h, NHALF);
    }

    k_expand_edge<<<(NB * DD / 4) / 256, 256, 0, stream>>>(
        (const float4*)half, (float4*)edge_out);

    hipMemsetAsync(graph, 0, DD * sizeof(float), stream);
    k_graph_mean<<<120, 256, 0, stream>>>(node, graph);
}

// Round 3
// 1655.814 us; speedup vs baseline: 2.3354x; 1.4211x over previous
//
#include <hip/hip_runtime.h>
#include <math.h>

#define NA 30000
#define NB 100000
#define NHALF 50000
#define NANG 200000
#define DD 128
#define HH 256
#define LL 8
#define MT 64   // rows per MLP block

typedef unsigned short ushort_t;
typedef unsigned int uint_t;
typedef short s16x8 __attribute__((ext_vector_type(8)));
typedef float f32x4 __attribute__((ext_vector_type(4)));

__device__ __forceinline__ ushort_t f2bf(float x) {
    unsigned int u = __builtin_bit_cast(unsigned int, x);
    u += 0x7fff + ((u >> 16) & 1);
    return (ushort_t)(u >> 16);
}
__device__ __forceinline__ float bf2f(ushort_t b) {
    unsigned int u = ((unsigned int)b) << 16;
    return __builtin_bit_cast(float, u);
}

// ---------------- node init
__global__ __launch_bounds__(256) void k_node_init(
    const int* __restrict__ cat, const float* __restrict__ emb,
    float* __restrict__ node)
{
    int tid = threadIdx.x;
    int r = blockIdx.x * 2 + (tid >> 7);
    int c = tid & 127;
    const int* cr = cat + r * 9;
    float v = 0.f;
    #pragma unroll
    for (int i = 0; i < 9; ++i) v += emb[((i << 6) + cr[i]) * DD + c];
    node[(size_t)r * DD + c] = v;
}

// ---------------- bond features (cat-embed + bond RBF), bf16 out; row i <- bond i*mul
__global__ __launch_bounds__(256) void k_bond_feat(
    const int* __restrict__ bcat, const float* __restrict__ bfloat,
    const float* __restrict__ emb, const float* __restrict__ rw,
    const float* __restrict__ rbv, ushort_t* __restrict__ out, int mul)
{
    __shared__ float sR[2][20];
    int tid = threadIdx.x;
    int sub = tid >> 7, c = tid & 127;
    int i = blockIdx.x * 2 + sub;
    int e = i * mul;
    if (c < 20) {
        float d = bfloat[e] - 0.1f * (float)c;
        sR[sub][c] = expf(-10.f * d * d);
    }
    __syncthreads();
    float v = rbv[c];
    #pragma unroll
    for (int k = 0; k < 20; ++k) v += sR[sub][k] * rw[k * DD + c];
    const int* bc = bcat + e * 3;
    #pragma unroll
    for (int j = 0; j < 3; ++j) v += emb[((j << 4) + bc[j]) * DD + c];
    out[(size_t)i * DD + c] = f2bf(v);
}

// ================= CSR build =================
__global__ __launch_bounds__(256) void k_hist(
    const int* __restrict__ dst, int* __restrict__ cur, int n)
{
    int i = blockIdx.x * 256 + threadIdx.x;
    if (i < n) atomicAdd(&cur[dst[i]], 1);
}

// blockIdx 0 = ab, 1 = ba. Exclusive scan cur -> rp, cur := row start.
__global__ __launch_bounds__(1024) void k_scan(
    int* __restrict__ cur_ab, int* __restrict__ rp_ab,
    int* __restrict__ cur_ba, int* __restrict__ rp_ba)
{
    int N; int* cur; int* rp;
    if (blockIdx.x == 0) { cur = cur_ab; rp = rp_ab; N = NA; }
    else                 { cur = cur_ba; rp = rp_ba; N = NHALF; }
    __shared__ int sp[1024];
    int tid = threadIdx.x;
    int carry = 0;
    for (int base = 0; base < N; base += 1024) {
        int idx = base + tid;
        int x = (idx < N) ? cur[idx] : 0;
        sp[tid] = x;
        __syncthreads();
        for (int off = 1; off < 1024; off <<= 1) {
            int t = (tid >= off) ? sp[tid - off] : 0;
            __syncthreads();
            sp[tid] += t;
            __syncthreads();
        }
        int inc = sp[tid];
        if (idx < N) { int ex = carry + inc - x; rp[idx] = ex; cur[idx] = ex; }
        int tot = sp[1023];
        __syncthreads();
        carry += tot;
    }
    if (tid == 0) rp[N] = carry;
}

__global__ __launch_bounds__(256) void k_fill_ab(
    const int* __restrict__ src, const int* __restrict__ dst,
    int* __restrict__ cur, int* __restrict__ psrc, int* __restrict__ peid)
{
    int i = blockIdx.x * 256 + threadIdx.x;
    if (i < NB) {
        int p = atomicAdd(&cur[dst[i]], 1);
        psrc[p] = src[i];
        peid[p] = i;
    }
}

__global__ __launch_bounds__(256) void k_fill_ba(
    const int* __restrict__ src, const int* __restrict__ dst,
    const float* __restrict__ ang,
    int* __restrict__ cur, int* __restrict__ psrc, float* __restrict__ pang)
{
    int i = blockIdx.x * 256 + threadIdx.x;
    if (i < NANG) {
        int p = atomicAdd(&cur[dst[i]], 1);
        psrc[p] = src[i];
        pang[p] = ang[i];
    }
}

// ================= gathers (no atomics) =================
template<bool L0>
__global__ __launch_bounds__(256) void k_gather_ab(
    const float* __restrict__ node, const void* __restrict__ edgefeat,
    const int* __restrict__ rp, const int* __restrict__ psrc,
    const int* __restrict__ peid, float* __restrict__ agg)
{
    int tid = threadIdx.x;
    int n = blockIdx.x * 2 + (tid >> 7);
    int c = tid & 127;
    int p0 = rp[n], p1 = rp[n + 1];
    float v = 0.f;
    for (int p = p0; p < p1; ++p) {
        int s = psrc[p], e = peid[p];
        float f = L0 ? bf2f(((const ushort_t*)edgefeat)[(size_t)e * DD + c])
                     : ((const float*)edgefeat)[(size_t)(e >> 1) * DD + c];
        v += node[(size_t)s * DD + c] + f;
    }
    agg[(size_t)n * DD + c] = v;
}

__global__ __launch_bounds__(256) void k_gather_ba(
    const uint_t* __restrict__ bemb2, const int* __restrict__ rp,
    const int* __restrict__ psrc, float2* __restrict__ agg2)
{
    int tid = threadIdx.x;
    int n = blockIdx.x * 4 + (tid >> 6);
    int lane = tid & 63;
    int p0 = rp[n], p1 = rp[n + 1];
    float v0 = 0.f, v1 = 0.f;
    for (int p = p0; p < p1; ++p) {
        uint_t u = bemb2[(size_t)psrc[p] * 64 + lane];
        v0 += bf2f((ushort_t)(u & 0xffff));
        v1 += bf2f((ushort_t)(u >> 16));
    }
    agg2[(size_t)n * 64 + lane] = make_float2(v0, v1);
}

__global__ __launch_bounds__(256) void k_gather_R(
    const float* __restrict__ pang, const int* __restrict__ rp,
    float* __restrict__ Ragg)
{
    int tid = threadIdx.x;
    int n = blockIdx.x * 8 + (tid >> 5);
    int k = tid & 31;
    float ctr = 0.1f * (float)k;
    int p0 = rp[n], p1 = rp[n + 1];
    float v = 0.f;
    for (int p = p0; p < p1; ++p) {
        float d = pang[p] - ctr;
        v += expf(-10.f * d * d);
    }
    Ragg[(size_t)n * 32 + k] = v;
}

// ================= weight precompute / packing =================
// rwW1[l][k][n] = sum_c rw[l][k][c] * ba_w1[l][c][n]   (8 x 32 x 256 fp32)
__global__ __launch_bounds__(256) void k_rwW1(
    const float* __restrict__ rw, const float* __restrict__ w1,
    float* __restrict__ out)
{
    int f = blockIdx.x * 256 + threadIdx.x;   // 65536
    int n = f & 255, k = (f >> 8) & 31, l = f >> 13;
    const float* rwl = rw + (size_t)l * 32 * DD + k * DD;
    const float* w1l = w1 + (size_t)l * DD * HH + n;
    float v = 0.f;
    for (int c = 0; c < DD; ++c) v += rwl[c] * w1l[(size_t)c * HH];
    out[(size_t)f] = v;
}

// rbvW1[l][n] = sum_c rbv[l][c] * ba_w1[l][c][n]
__global__ __launch_bounds__(256) void k_rbvW1(
    const float* __restrict__ rbv, const float* __restrict__ w1,
    float* __restrict__ out)
{
    int f = blockIdx.x * 256 + threadIdx.x;   // 2048
    int n = f & 255, l = f >> 8;
    const float* rl = rbv + (size_t)l * DD;
    const float* w1l = w1 + (size_t)l * DD * HH + n;
    float v = 0.f;
    for (int c = 0; c < DD; ++c) v += rl[c] * w1l[(size_t)c * HH];
    out[(size_t)f] = v;
}

// ab w1: per layer 8 chunks x [tl(2)][s(4)][lane(64)][8]
__global__ __launch_bounds__(256) void k_pack_w1_ab(
    const float* __restrict__ w1, ushort_t* __restrict__ wp)
{
    int f = blockIdx.x * 256 + threadIdx.x;   // 32768
    int lane = f & 63, s = (f >> 6) & 3, tl = (f >> 8) & 1, c = (f >> 9) & 7, l = f >> 12;
    const float* W = w1 + (size_t)l * DD * HH;
    int k0 = s * 32 + (lane >> 4) * 8;
    int n = (2 * c + tl) * 16 + (lane & 15);
    ushort_t* d = wp + (size_t)l * 32768 + c * 4096 + tl * 2048 + s * 512 + lane * 8;
    ushort_t tmp[8];
    #pragma unroll
    for (int j = 0; j < 8; ++j) tmp[j] = f2bf(W[(size_t)(k0 + j) * HH + n]);
    unsigned int pk[4];
    #pragma unroll
    for (int j = 0; j < 4; ++j) pk[j] = (uint_t)tmp[2*j] | ((uint_t)tmp[2*j+1] << 16);
    *(uint4*)d = make_uint4(pk[0], pk[1], pk[2], pk[3]);
}

// ba w1 ext: per layer 8 chunks x [tl(2)][s(5)][lane(64)][8]; s==4 from rwW1
__global__ __launch_bounds__(64) void k_pack_w1_ba(
    const float* __restrict__ w1, const float* __restrict__ rwW1buf,
    ushort_t* __restrict__ wp)
{
    int bi = blockIdx.x;             // 640 = 8l * 8c * 2tl * 5s
    int lane = threadIdx.x;
    int s = bi % 5; int r2 = bi / 5;
    int tl = r2 & 1; int c = (r2 >> 1) & 7; int l = r2 >> 4;
    int n = (2 * c + tl) * 16 + (lane & 15);
    const float* W; int k0;
    if (s < 4) { W = w1 + (size_t)l * DD * HH; k0 = s * 32 + (lane >> 4) * 8; }
    else       { W = rwW1buf + (size_t)l * 32 * HH; k0 = (lane >> 4) * 8; }
    ushort_t* d = wp + (size_t)l * 40960 + c * 5120 + tl * 2560 + s * 512 + lane * 8;
    ushort_t tmp[8];
    #pragma unroll
    for (int j = 0; j < 8; ++j) tmp[j] = f2bf(W[(size_t)(k0 + j) * HH + n]);
    unsigned int pk[4];
    #pragma unroll
    for (int j = 0; j < 4; ++j) pk[j] = (uint_t)tmp[2*j] | ((uint_t)tmp[2*j+1] << 16);
    *(uint4*)d = make_uint4(pk[0], pk[1], pk[2], pk[3]);
}

// w2 (both groups): per layer 8 chunks(t) x [s(8)][lane(64)][8]
__global__ __launch_bounds__(256) void k_pack_w2(
    const float* __restrict__ ab_w2, const float* __restrict__ ba_w2,
    ushort_t* __restrict__ wp)
{
    int f = blockIdx.x * 256 + threadIdx.x;   // 65536
    int lane = f & 63, s = (f >> 6) & 7, t = (f >> 9) & 7, l = (f >> 12) & 7, grp = f >> 15;
    const float* W = (grp ? ba_w2 : ab_w2) + (size_t)l * HH * DD;
    int k0 = s * 32 + (lane >> 4) * 8;
    int n = t * 16 + (lane & 15);
    ushort_t* d = wp + (size_t)grp * 262144 + (size_t)l * 32768 + t * 4096 + s * 512 + lane * 8;
    ushort_t tmp[8];
    #pragma unroll
    for (int j = 0; j < 8; ++j) tmp[j] = f2bf(W[(size_t)(k0 + j) * DD + n]);
    unsigned int pk[4];
    #pragma unroll
    for (int j = 0; j < 4; ++j) pk[j] = (uint_t)tmp[2*j] | ((uint_t)tmp[2*j+1] << 16);
    *(uint4*)d = make_uint4(pk[0], pk[1], pk[2], pk[3]);
}

// ================= MFMA fused MLP =================
// EXT (ba): K extended to 160 (R_agg via rw@W1) + deg*(rbv@W1); residual bf16.
// !EXT (ab): K=128; residual fp32.
template<bool EXT>
__global__ __launch_bounds__(256) void k_mlp_mfma(
    const float* __restrict__ agg, const void* __restrict__ node_in,
    const ushort_t* __restrict__ w1p, const float* __restrict__ b1,
    const ushort_t* __restrict__ w2p, const float* __restrict__ b2,
    const float* __restrict__ g, const float* __restrict__ bt,
    const float* __restrict__ Ragg, const int* __restrict__ rp,
    const float* __restrict__ rbvW1,
    float* __restrict__ out, float inv_sqrt_n, int nrows)
{
    constexpr int AS = EXT ? 160 : 136;
    constexpr int KS = EXT ? 5 : 4;
    __shared__ __align__(16) ushort_t sA[MT][AS];
    __shared__ __align__(16) ushort_t sC1[MT][264];
    __shared__ __align__(16) ushort_t sW[KS * 1024];

    const int tid = threadIdx.x;
    const int wid = tid >> 6, lane = tid & 63;
    const int row0 = blockIdx.x * MT;

    // ---- A-phase: agg fp32 -> bf16 tile
    {
        const float4* a4 = (const float4*)agg;
        #pragma unroll
        for (int i = 0; i < 8; ++i) {
            int idx = tid + i * 256;
            int row = idx >> 5, c4 = idx & 31;
            int grow = row0 + row;
            float4 v = make_float4(0.f, 0.f, 0.f, 0.f);
            if (grow < nrows) v = a4[(size_t)grow * 32 + c4];
            unsigned int lo = (uint_t)f2bf(v.x) | ((uint_t)f2bf(v.y) << 16);
            unsigned int hi = (uint_t)f2bf(v.z) | ((uint_t)f2bf(v.w) << 16);
            *(uint2*)&sA[row][c4 * 4] = make_uint2(lo, hi);
        }
    }
    float dg[4];
    if (EXT) {
        const float4* r4 = (const float4*)Ragg;
        #pragma unroll
        for (int i = 0; i < 2; ++i) {
            int idx = tid + i * 256;
            int row = idx >> 3, c4 = idx & 7;
            int grow = row0 + row;
            float4 v = make_float4(0.f, 0.f, 0.f, 0.f);
            if (grow < nrows) v = r4[(size_t)grow * 8 + c4];
            unsigned int lo = (uint_t)f2bf(v.x) | ((uint_t)f2bf(v.y) << 16);
            unsigned int hi = (uint_t)f2bf(v.z) | ((uint_t)f2bf(v.w) << 16);
            *(uint2*)&sA[row][128 + c4 * 4] = make_uint2(lo, hi);
        }
        int r0g = row0 + wid * 16 + ((lane >> 4) << 2);
        #pragma unroll
        for (int r = 0; r < 4; ++r) {
            int gr = r0g + r;
            dg[r] = (gr < nrows) ? (float)(rp[gr + 1] - rp[gr]) : 0.f;
        }
    }
    __syncthreads();

    // ---- A fragments
    const int arow = wid * 16 + (lane & 15);
    const int acol = (lane >> 4) * 8;
    s16x8 af[KS];
    #pragma unroll
    for (int s = 0; s < KS; ++s) af[s] = *(const s16x8*)&sA[arow][s * 32 + acol];

    // ---- GEMM1: 8 chunks of 32 cols
    for (int c = 0; c < 8; ++c) {
        const float4* srcw = (const float4*)(w1p + c * (KS * 1024));
        float4* dstw = (float4*)sW;
        dstw[tid] = srcw[tid];
        dstw[tid + 256] = srcw[tid + 256];
        if (EXT && tid < 128) dstw[tid + 512] = srcw[tid + 512];
        __syncthreads();
        #pragma unroll
        for (int tl = 0; tl < 2; ++tl) {
            int t = c * 2 + tl;
            f32x4 acc = {0.f, 0.f, 0.f, 0.f};
            #pragma unroll
            for (int s = 0; s < KS; ++s) {
                s16x8 bf = *(const s16x8*)&sW[(tl * KS + s) * 512 + lane * 8];
                acc = __builtin_amdgcn_mfma_f32_16x16x32_bf16(af[s], bf, acc, 0, 0, 0);
            }
            int n = t * 16 + (lane & 15);
            float b1v = b1[n];
            float rbn = EXT ? rbvW1[n] : 0.f;
            int r0 = wid * 16 + ((lane >> 4) << 2);
            #pragma unroll
            for (int r = 0; r < 4; ++r) {
                float h = acc[r] + b1v;
                if (EXT) h += dg[r] * rbn;
                sC1[r0 + r][n] = f2bf(fmaxf(h, 0.f));
            }
        }
        __syncthreads();
    }

    // ---- A2 fragments from hidden
    s16x8 a2[8];
    #pragma unroll
    for (int s = 0; s < 8; ++s) a2[s] = *(const s16x8*)&sC1[arow][s * 32 + acol];

    // ---- GEMM2: 8 chunks of 16 cols
    f32x4 c2[8];
    for (int t = 0; t < 8; ++t) {
        const float4* srcw = (const float4*)(w2p + t * 4096);
        float4* dstw = (float4*)sW;
        dstw[tid] = srcw[tid];
        dstw[tid + 256] = srcw[tid + 256];
        __syncthreads();
        f32x4 acc = {0.f, 0.f, 0.f, 0.f};
        #pragma unroll
        for (int s = 0; s < 8; ++s) {
            s16x8 bf = *(const s16x8*)&sW[(s * 64 + lane) * 8];
            acc = __builtin_amdgcn_mfma_f32_16x16x32_bf16(a2[s], bf, acc, 0, 0, 0);
        }
        c2[t] = acc;
        __syncthreads();
    }

    // ---- epilogue: +b2, LN, *g+bt, /sqrt(n), relu, +residual
    const int colb = lane & 15;
    float b2v[8], gv[8], btv[8];
    #pragma unroll
    for (int t = 0; t < 8; ++t) {
        int n = t * 16 + colb;
        b2v[t] = b2[n]; gv[t] = g[n]; btv[t] = bt[n];
    }
    #pragma unroll
    for (int t = 0; t < 8; ++t)
        #pragma unroll
        for (int r = 0; r < 4; ++r) c2[t][r] += b2v[t];

    #pragma unroll
    for (int r = 0; r < 4; ++r) {
        float s = 0.f, ss = 0.f;
        #pragma unroll
        for (int t = 0; t < 8; ++t) { float x = c2[t][r]; s += x; ss += x * x; }
        #pragma unroll
        for (int m = 1; m < 16; m <<= 1) {
            s  += __shfl_xor(s, m);
            ss += __shfl_xor(ss, m);
        }
        float mu = s * (1.f / 128.f);
        float var = ss * (1.f / 128.f) - mu * mu;
        float rstd = rsqrtf(var + 1e-5f);
        int grow = row0 + wid * 16 + ((lane >> 4) << 2) + r;
        if (grow < nrows) {
            #pragma unroll
            for (int t = 0; t < 8; ++t) {
                int n = t * 16 + colb;
                float y = (c2[t][r] - mu) * rstd * gv[t] + btv[t];
                float res = EXT
                    ? bf2f(((const ushort_t*)node_in)[(size_t)grow * DD + n])
                    : ((const float*)node_in)[(size_t)grow * DD + n];
                out[(size_t)grow * DD + n] = fmaxf(y * inv_sqrt_n, 0.f) + res;
            }
        }
    }
}

// ---------------- final edge = repeat(half, 2)
__global__ __launch_bounds__(256) void k_expand_edge(
    const float4* __restrict__ half, float4* __restrict__ out)
{
    int t = blockIdx.x * 256 + threadIdx.x;
    out[t] = half[((t >> 6) << 5) | (t & 31)];
}

// ---------------- graph = node.mean(axis=0)
__global__ __launch_bounds__(256) void k_graph_mean(
    const float* __restrict__ node, float* __restrict__ graph)
{
    int tid = threadIdx.x;
    int c = tid & 127, h = tid >> 7;
    const int rpb = 250;
    int r0 = blockIdx.x * rpb;
    float s = 0.f;
    for (int r = r0 + h; r < r0 + rpb; r += 2) s += node[(size_t)r * DD + c];
    __shared__ float sS[256];
    sS[tid] = s;
    __syncthreads();
    if (tid < 128) atomicAdd(&graph[c], (sS[tid] + sS[tid + 128]) * (1.f / 30000.f));
}

extern "C" void kernel_launch(void* const* d_in, const int* in_sizes, int n_in,
                              void* d_out, int out_size, void* d_ws, size_t ws_size,
                              hipStream_t stream)
{
    const int*   atom_cat         = (const int*)d_in[0];
    const int*   bond_cat         = (const int*)d_in[1];
    const float* bond_float       = (const float*)d_in[2];
    const float* angle_float      = (const float*)d_in[3];
    const int*   ab_src           = (const int*)d_in[4];
    const int*   ab_dst           = (const int*)d_in[5];
    const int*   ba_src           = (const int*)d_in[6];
    const int*   ba_dst           = (const int*)d_in[7];
    const float* atom_emb         = (const float*)d_in[8];
    const float* bond_emb_init    = (const float*)d_in[9];
    const float* bond_rbf_w_init  = (const float*)d_in[10];
    const float* bond_rbf_b_init  = (const float*)d_in[11];
    const float* layer_bond_emb   = (const float*)d_in[12];
    const float* layer_bond_rbf_w = (const float*)d_in[13];
    const float* layer_bond_rbf_b = (const float*)d_in[14];
    const float* layer_angle_rbf_w= (const float*)d_in[15];
    const float* layer_angle_rbf_b= (const float*)d_in[16];
    const float* ab_w1 = (const float*)d_in[17];
    const float* ab_b1 = (const float*)d_in[18];
    const float* ab_w2 = (const float*)d_in[19];
    const float* ab_b2 = (const float*)d_in[20];
    const float* ab_g  = (const float*)d_in[21];
    const float* ab_bt = (const float*)d_in[22];
    const float* ba_w1 = (const float*)d_in[23];
    const float* ba_b1 = (const float*)d_in[24];
    const float* ba_w2 = (const float*)d_in[25];
    const float* ba_b2 = (const float*)d_in[26];
    const float* ba_g  = (const float*)d_in[27];
    const float* ba_bt = (const float*)d_in[28];

    float* node     = (float*)d_out;                  // NA*DD
    float* edge_out = node + (size_t)NA * DD;         // NB*DD
    float* graph    = edge_out + (size_t)NB * DD;     // DD

    // ---- ws layout
    float*    agg      = (float*)d_ws;                        // 50000*128 f32
    float*    half     = agg + (size_t)NHALF * DD;            // 50000*128 f32 (aliases einit)
    ushort_t* einit    = (ushort_t*)half;                     // 100000*128 bf16 (layer-0 only)
    ushort_t* bemb     = (ushort_t*)(half + (size_t)NHALF * DD);  // 50000*128 bf16
    float*    Ragg     = (float*)(bemb + (size_t)NHALF * DD); // 50000*32 f32
    float*    rwW1buf  = Ragg + (size_t)NHALF * 32;           // 8*32*256 f32
    float*    rbvW1    = rwW1buf + 65536;                     // 8*256 f32
    ushort_t* wp_ab_w1 = (ushort_t*)(rbvW1 + 2048);           // 8*32768
    ushort_t* wp_ba_w1 = wp_ab_w1 + 8 * 32768;                // 8*40960
    ushort_t* wp_w2    = wp_ba_w1 + 8 * 40960;                // 2*8*32768
    int*      rp_ab    = (int*)(wp_w2 + 2 * 8 * 32768);       // 30001
    int*      cur_ab   = rp_ab + NA + 1;                      // 30000
    int*      psrc_ab  = cur_ab + NA;                         // 100000
    int*      peid_ab  = psrc_ab + NB;                        // 100000
    int*      rp_ba    = peid_ab + NB;                        // 50001
    int*      cur_ba   = rp_ba + NHALF + 1;                   // 50000
    int*      psrc_ba  = cur_ba + NHALF;                      // 200000
    float*    pang     = (float*)(psrc_ba + NANG);            // 200000

    const float isn_a = (float)(1.0 / sqrt(30000.0));
    const float isn_h = (float)(1.0 / sqrt(50000.0));

    // ---- CSR build (once; graphs static across layers)
    hipMemsetAsync(cur_ab, 0, NA * sizeof(int), stream);
    hipMemsetAsync(cur_ba, 0, NHALF * sizeof(int), stream);
    k_hist<<<(NB + 255) / 256, 256, 0, stream>>>(ab_dst, cur_ab, NB);
    k_hist<<<(NANG + 255) / 256, 256, 0, stream>>>(ba_dst, cur_ba, NANG);
    k_scan<<<2, 1024, 0, stream>>>(cur_ab, rp_ab, cur_ba, rp_ba);
    k_fill_ab<<<(NB + 255) / 256, 256, 0, stream>>>(ab_src, ab_dst, cur_ab, psrc_ab, peid_ab);
    k_fill_ba<<<(NANG + 255) / 256, 256, 0, stream>>>(ba_src, ba_dst, angle_float, cur_ba, psrc_ba, pang);

    // ---- weight precompute + packing (once)
    k_rwW1<<<256, 256, 0, stream>>>(layer_angle_rbf_w, ba_w1, rwW1buf);
    k_rbvW1<<<8, 256, 0, stream>>>(layer_angle_rbf_b, ba_w1, rbvW1);
    k_pack_w1_ab<<<128, 256, 0, stream>>>(ab_w1, wp_ab_w1);
    k_pack_w1_ba<<<640, 64, 0, stream>>>(ba_w1, rwW1buf, wp_ba_w1);
    k_pack_w2<<<256, 256, 0, stream>>>(ab_w2, ba_w2, wp_w2);

    // ---- node init + layer-0 full-bond edge features
    k_node_init<<<NA / 2, 256, 0, stream>>>(atom_cat, atom_emb, node);
    k_bond_feat<<<NB / 2, 256, 0, stream>>>(bond_cat, bond_float, bond_emb_init,
        bond_rbf_w_init, bond_rbf_b_init, einit, 1);

    for (int l = 0; l < LL; ++l) {
        const ushort_t* ab_w1p = wp_ab_w1 + (size_t)l * 32768;
        const ushort_t* ba_w1p = wp_ba_w1 + (size_t)l * 40960;
        const ushort_t* ab_w2p = wp_w2 + (size_t)l * 32768;
        const ushort_t* ba_w2p = wp_w2 + (size_t)(8 + l) * 32768;

        if (l == 0)
            k_gather_ab<true><<<NA / 2, 256, 0, stream>>>(node, einit, rp_ab, psrc_ab, peid_ab, agg);
        else
            k_gather_ab<false><<<NA / 2, 256, 0, stream>>>(node, half, rp_ab, psrc_ab, peid_ab, agg);

        k_mlp_mfma<false><<<(NA + MT - 1) / MT, 256, 0, stream>>>(
            agg, node, ab_w1p, ab_b1 + l * HH, ab_w2p, ab_b2 + l * DD,
            ab_g + l * DD, ab_bt + l * DD, nullptr, nullptr, nullptr,
            node, isn_a, NA);

        k_bond_feat<<<NHALF / 2, 256, 0, stream>>>(bond_cat, bond_float,
            layer_bond_emb + (size_t)l * 3 * 16 * DD,
            layer_bond_rbf_w + (size_t)l * 20 * DD,
            layer_bond_rbf_b + l * DD, bemb, 2);

        k_gather_ba<<<NHALF / 4, 256, 0, stream>>>((const uint_t*)bemb, rp_ba, psrc_ba, (float2*)agg);
        k_gather_R<<<NHALF / 8, 256, 0, stream>>>(pang, rp_ba, Ragg);

        k_mlp_mfma<true><<<(NHALF + MT - 1) / MT, 256, 0, stream>>>(
            agg, bemb, ba_w1p, ba_b1 + l * HH, ba_w2p, ba_b2 + l * DD,
            ba_g + l * DD, ba_bt + l * DD, Ragg, rp_ba, rbvW1,
            half, isn_h, NHALF);
    }

    k_expand_edge<<<(NB * DD / 4) / 256, 256, 0, stream>>>(
        (const float4*)half, (float4*)edge_out);

    hipMemsetAsync(graph, 0, DD * sizeof(float), stream);
    k_graph_mean<<<120, 256, 0, stream>>>(node, graph);
}

// Round 4
// 1172.349 us; speedup vs baseline: 3.2985x; 1.4124x over previous
//
#include <hip/hip_runtime.h>
#include <math.h>

#define NA 30000
#define NB 100000
#define NHALF 50000
#define NANG 200000
#define DD 128
#define HH 256
#define LL 8
#define MT 64   // rows per MLP block

typedef unsigned short ushort_t;
typedef unsigned int uint_t;
typedef short s16x8 __attribute__((ext_vector_type(8)));
typedef float f32x4 __attribute__((ext_vector_type(4)));

__device__ __forceinline__ ushort_t f2bf(float x) {
    unsigned int u = __builtin_bit_cast(unsigned int, x);
    u += 0x7fff + ((u >> 16) & 1);
    return (ushort_t)(u >> 16);
}
__device__ __forceinline__ float bf2f(ushort_t b) {
    unsigned int u = ((unsigned int)b) << 16;
    return __builtin_bit_cast(float, u);
}

// ---------------- node init (fp32 + bf16 shadow)
__global__ __launch_bounds__(256) void k_node_init(
    const int* __restrict__ cat, const float* __restrict__ emb,
    float* __restrict__ node, ushort_t* __restrict__ node_bf)
{
    int tid = threadIdx.x;
    int r = blockIdx.x * 2 + (tid >> 7);
    int c = tid & 127;
    const int* cr = cat + r * 9;
    float v = 0.f;
    #pragma unroll
    for (int i = 0; i < 9; ++i) v += emb[((i << 6) + cr[i]) * DD + c];
    node[(size_t)r * DD + c] = v;
    node_bf[(size_t)r * DD + c] = f2bf(v);
}

// ---------------- bond features (cat-embed + bond RBF), bf16 out; row i <- bond i*mul
__global__ __launch_bounds__(256) void k_bond_feat(
    const int* __restrict__ bcat, const float* __restrict__ bfloat,
    const float* __restrict__ emb, const float* __restrict__ rw,
    const float* __restrict__ rbv, ushort_t* __restrict__ out, int mul)
{
    __shared__ float sR[2][20];
    int tid = threadIdx.x;
    int sub = tid >> 7, c = tid & 127;
    int i = blockIdx.x * 2 + sub;
    int e = i * mul;
    if (c < 20) {
        float d = bfloat[e] - 0.1f * (float)c;
        sR[sub][c] = expf(-10.f * d * d);
    }
    __syncthreads();
    float v = rbv[c];
    #pragma unroll
    for (int k = 0; k < 20; ++k) v += sR[sub][k] * rw[k * DD + c];
    const int* bc = bcat + e * 3;
    #pragma unroll
    for (int j = 0; j < 3; ++j) v += emb[((j << 4) + bc[j]) * DD + c];
    out[(size_t)i * DD + c] = f2bf(v);
}

// ================= CSR build =================
__global__ __launch_bounds__(256) void k_hist2(
    const int* __restrict__ ab_dst, int* __restrict__ cur_ab,
    const int* __restrict__ ba_dst, int* __restrict__ cur_ba)
{
    int i = blockIdx.x * 256 + threadIdx.x;
    if (i < NB) atomicAdd(&cur_ab[ab_dst[i]], 1);
    int j = i - NB;
    if (j >= 0 && j < NANG) atomicAdd(&cur_ba[ba_dst[j]], 1);
}

// blockIdx 0 = ab, 1 = ba. Exclusive scan cur -> rp, cur := row start.
// Shuffle-based: 3 barriers per 1024-chunk.
__global__ __launch_bounds__(1024) void k_scan(
    int* __restrict__ cur_ab, int* __restrict__ rp_ab,
    int* __restrict__ cur_ba, int* __restrict__ rp_ba)
{
    int N; int* cur; int* rp;
    if (blockIdx.x == 0) { cur = cur_ab; rp = rp_ab; N = NA; }
    else                 { cur = cur_ba; rp = rp_ba; N = NHALF; }
    __shared__ int sw[16];
    __shared__ int scarry;
    int tid = threadIdx.x;
    int wid = tid >> 6, lane = tid & 63;
    if (tid == 0) scarry = 0;
    __syncthreads();
    for (int base = 0; base < N; base += 1024) {
        int idx = base + tid;
        int x = (idx < N) ? cur[idx] : 0;
        int v = x;
        #pragma unroll
        for (int off = 1; off < 64; off <<= 1) {
            int t = __shfl_up(v, off);
            if (lane >= off) v += t;
        }
        if (lane == 63) sw[wid] = v;
        __syncthreads();
        if (wid == 0) {
            int wv = (lane < 16) ? sw[lane] : 0;
            #pragma unroll
            for (int off = 1; off < 16; off <<= 1) {
                int t = __shfl_up(wv, off);
                if (lane >= off) wv += t;
            }
            if (lane < 16) sw[lane] = wv;
        }
        __syncthreads();
        int wpre = (wid > 0) ? sw[wid - 1] : 0;
        int carry = scarry;
        int ex = carry + wpre + v - x;
        if (idx < N) { rp[idx] = ex; cur[idx] = ex; }
        __syncthreads();
        if (tid == 1023) scarry = carry + sw[15];
        __syncthreads();
    }
    if (tid == 0) rp[N] = scarry;
}

__global__ __launch_bounds__(256) void k_fill_ab(
    const int* __restrict__ src, const int* __restrict__ dst,
    int* __restrict__ cur, int* __restrict__ psrc, int* __restrict__ peid)
{
    int i = blockIdx.x * 256 + threadIdx.x;
    if (i < NB) {
        int p = atomicAdd(&cur[dst[i]], 1);
        psrc[p] = src[i];
        peid[p] = i;
    }
}

__global__ __launch_bounds__(256) void k_fill_ba(
    const int* __restrict__ src, const int* __restrict__ dst,
    const float* __restrict__ ang,
    int* __restrict__ cur, int* __restrict__ psrc, float* __restrict__ pang)
{
    int i = blockIdx.x * 256 + threadIdx.x;
    if (i < NANG) {
        int p = atomicAdd(&cur[dst[i]], 1);
        psrc[p] = src[i];
        pang[p] = ang[i];
    }
}

// ================= ba layer-invariant feature matrix =================
// Aext[n] = [H48 | Rb20 | Rang32 | deg | 0pad27]  (bf16, 128 cols)
__global__ __launch_bounds__(256) void k_feat_ext(
    const int* __restrict__ rp, const int* __restrict__ psrc,
    const float* __restrict__ pang, const float* __restrict__ bfloat,
    const int* __restrict__ bcat, ushort_t* __restrict__ Aext)
{
    int tid = threadIdx.x;
    int sub = tid >> 7, c = tid & 127;
    int n = blockIdx.x * 2 + sub;
    int p0 = rp[n], p1 = rp[n + 1];
    float v = 0.f;
    for (int p = p0; p < p1; ++p) {
        int s = psrc[p];
        if (c < 48) {
            v += (bcat[s * 6 + (c >> 4)] == (c & 15)) ? 1.f : 0.f;
        } else if (c < 68) {
            float d = bfloat[2 * s] - 0.1f * (float)(c - 48);
            v += expf(-10.f * d * d);
        } else if (c < 100) {
            float d = pang[p] - 0.1f * (float)(c - 68);
            v += expf(-10.f * d * d);
        } else if (c == 100) {
            v += 1.f;
        }
    }
    Aext[(size_t)n * DD + c] = f2bf(v);
}

// W1ext[l][k][n] (8 x 128 x 256 fp32): folded GEMM1 weights for ba path
__global__ __launch_bounds__(256) void k_w1ext(
    const float* __restrict__ ba_w1, const float* __restrict__ lbemb,
    const float* __restrict__ rwb, const float* __restrict__ rbvb,
    const float* __restrict__ rwa, const float* __restrict__ rbva,
    float* __restrict__ W1ext)
{
    int f = blockIdx.x * 256 + threadIdx.x;   // 262144
    int n = f & 255, k = (f >> 8) & 127, l = f >> 15;
    float v = 0.f;
    if (k <= 100) {
        const float* w1 = ba_w1 + (size_t)l * DD * HH + n;
        if (k == 100) {
            const float* r1 = rbvb + (size_t)l * DD;
            const float* r2 = rbva + (size_t)l * DD;
            for (int c = 0; c < DD; ++c) v += (r1[c] + r2[c]) * w1[(size_t)c * HH];
        } else {
            const float* row =
                (k < 48) ? lbemb + ((size_t)l * 48 + k) * DD :
                (k < 68) ? rwb + ((size_t)l * 20 + (k - 48)) * DD :
                           rwa + ((size_t)l * 32 + (k - 68)) * DD;
            for (int c = 0; c < DD; ++c) v += row[c] * w1[(size_t)c * HH];
        }
    }
    W1ext[f] = v;
}

// ================= gather ab (all-bf16) =================
template<bool L0>
__global__ __launch_bounds__(256) void k_gather_ab(
    const uint_t* __restrict__ node2, const uint_t* __restrict__ feat2,
    const int* __restrict__ rp, const int* __restrict__ psrc,
    const int* __restrict__ peid, uint_t* __restrict__ agg2)
{
    int tid = threadIdx.x;
    int n = blockIdx.x * 4 + (tid >> 6);
    int lane = tid & 63;
    int p0 = rp[n], p1 = rp[n + 1];
    float v0 = 0.f, v1 = 0.f;
    for (int p = p0; p < p1; ++p) {
        int s = psrc[p], e = peid[p];
        uint_t a = node2[(size_t)s * 64 + lane];
        uint_t b = feat2[(size_t)(L0 ? e : (e >> 1)) * 64 + lane];
        v0 += bf2f((ushort_t)(a & 0xffff)) + bf2f((ushort_t)(b & 0xffff));
        v1 += bf2f((ushort_t)(a >> 16)) + bf2f((ushort_t)(b >> 16));
    }
    agg2[(size_t)n * 64 + lane] = (uint_t)f2bf(v0) | ((uint_t)f2bf(v1) << 16);
}

// ================= weight packing =================
// w1 (128x256 per layer, fp32 row-major): per layer 8 chunks x [tl(2)][s(4)][lane(64)][8]
__global__ __launch_bounds__(256) void k_pack_w1(
    const float* __restrict__ w1src, ushort_t* __restrict__ wp)
{
    int f = blockIdx.x * 256 + threadIdx.x;   // 32768
    int lane = f & 63, s = (f >> 6) & 3, tl = (f >> 8) & 1, c = (f >> 9) & 7, l = f >> 12;
    const float* W = w1src + (size_t)l * DD * HH;
    int k0 = s * 32 + (lane >> 4) * 8;
    int n = (2 * c + tl) * 16 + (lane & 15);
    ushort_t* d = wp + (size_t)l * 32768 + c * 4096 + tl * 2048 + s * 512 + lane * 8;
    ushort_t tmp[8];
    #pragma unroll
    for (int j = 0; j < 8; ++j) tmp[j] = f2bf(W[(size_t)(k0 + j) * HH + n]);
    unsigned int pk[4];
    #pragma unroll
    for (int j = 0; j < 4; ++j) pk[j] = (uint_t)tmp[2*j] | ((uint_t)tmp[2*j+1] << 16);
    *(uint4*)d = make_uint4(pk[0], pk[1], pk[2], pk[3]);
}

// w2 (both groups): per layer 8 chunks(t) x [s(8)][lane(64)][8]
__global__ __launch_bounds__(256) void k_pack_w2(
    const float* __restrict__ ab_w2, const float* __restrict__ ba_w2,
    ushort_t* __restrict__ wp)
{
    int f = blockIdx.x * 256 + threadIdx.x;   // 65536
    int lane = f & 63, s = (f >> 6) & 7, t = (f >> 9) & 7, l = (f >> 12) & 7, grp = f >> 15;
    const float* W = (grp ? ba_w2 : ab_w2) + (size_t)l * HH * DD;
    int k0 = s * 32 + (lane >> 4) * 8;
    int n = t * 16 + (lane & 15);
    ushort_t* d = wp + (size_t)grp * 262144 + (size_t)l * 32768 + t * 4096 + s * 512 + lane * 8;
    ushort_t tmp[8];
    #pragma unroll
    for (int j = 0; j < 8; ++j) tmp[j] = f2bf(W[(size_t)(k0 + j) * DD + n]);
    unsigned int pk[4];
    #pragma unroll
    for (int j = 0; j < 4; ++j) pk[j] = (uint_t)tmp[2*j] | ((uint_t)tmp[2*j+1] << 16);
    *(uint4*)d = make_uint4(pk[0], pk[1], pk[2], pk[3]);
}

// ================= MFMA fused MLP (K=128) =================
// RES_BF16 (ba): residual bf16, output bf16 only. !RES_BF16 (ab): residual fp32,
// output fp32 + bf16 shadow.
template<bool RES_BF16>
__global__ __launch_bounds__(256) void k_mlp_mfma(
    const ushort_t* __restrict__ Abf, const void* __restrict__ resid,
    const ushort_t* __restrict__ w1p, const float* __restrict__ b1,
    const ushort_t* __restrict__ w2p, const float* __restrict__ b2,
    const float* __restrict__ g, const float* __restrict__ bt,
    float* __restrict__ outf, ushort_t* __restrict__ outb,
    float inv_sqrt_n, int nrows)
{
    __shared__ __align__(16) ushort_t sA[MT][136];
    __shared__ __align__(16) ushort_t sC1[MT][264];
    __shared__ __align__(16) ushort_t sW[4096];

    const int tid = threadIdx.x;
    const int wid = tid >> 6, lane = tid & 63;
    const int row0 = blockIdx.x * MT;

    // ---- A-phase: 64x128 bf16 tile
    #pragma unroll
    for (int i = 0; i < 4; ++i) {
        int idx = tid + i * 256;       // ushort8 units (1024)
        int row = idx >> 4, c8 = idx & 15;
        int grow = row0 + row;
        uint4 v = make_uint4(0, 0, 0, 0);
        if (grow < nrows) v = *(const uint4*)(Abf + (size_t)grow * DD + c8 * 8);
        *(uint4*)&sA[row][c8 * 8] = v;
    }
    __syncthreads();

    // ---- A fragments
    const int arow = wid * 16 + (lane & 15);
    const int acol = (lane >> 4) * 8;
    s16x8 af[4];
    #pragma unroll
    for (int s = 0; s < 4; ++s) af[s] = *(const s16x8*)&sA[arow][s * 32 + acol];

    // ---- GEMM1: 8 chunks of 32 cols
    for (int c = 0; c < 8; ++c) {
        const float4* srcw = (const float4*)(w1p + (c << 12));
        float4* dstw = (float4*)sW;
        dstw[tid] = srcw[tid];
        dstw[tid + 256] = srcw[tid + 256];
        __syncthreads();
        #pragma unroll
        for (int tl = 0; tl < 2; ++tl) {
            int t = c * 2 + tl;
            f32x4 acc = {0.f, 0.f, 0.f, 0.f};
            #pragma unroll
            for (int s = 0; s < 4; ++s) {
                s16x8 bf = *(const s16x8*)&sW[(tl * 4 + s) * 512 + lane * 8];
                acc = __builtin_amdgcn_mfma_f32_16x16x32_bf16(af[s], bf, acc, 0, 0, 0);
            }
            int n = t * 16 + (lane & 15);
            float b1v = b1[n];
            int r0 = wid * 16 + ((lane >> 4) << 2);
            #pragma unroll
            for (int r = 0; r < 4; ++r)
                sC1[r0 + r][n] = f2bf(fmaxf(acc[r] + b1v, 0.f));
        }
        __syncthreads();
    }

    // ---- A2 fragments from hidden
    s16x8 a2[8];
    #pragma unroll
    for (int s = 0; s < 8; ++s) a2[s] = *(const s16x8*)&sC1[arow][s * 32 + acol];

    // ---- GEMM2: 8 chunks of 16 cols
    f32x4 c2[8];
    for (int t = 0; t < 8; ++t) {
        const float4* srcw = (const float4*)(w2p + (t << 12));
        float4* dstw = (float4*)sW;
        dstw[tid] = srcw[tid];
        dstw[tid + 256] = srcw[tid + 256];
        __syncthreads();
        f32x4 acc = {0.f, 0.f, 0.f, 0.f};
        #pragma unroll
        for (int s = 0; s < 8; ++s) {
            s16x8 bf = *(const s16x8*)&sW[(s * 64 + lane) * 8];
            acc = __builtin_amdgcn_mfma_f32_16x16x32_bf16(a2[s], bf, acc, 0, 0, 0);
        }
        c2[t] = acc;
        __syncthreads();
    }

    // ---- epilogue
    const int colb = lane & 15;
    float b2v[8], gv[8], btv[8];
    #pragma unroll
    for (int t = 0; t < 8; ++t) {
        int n = t * 16 + colb;
        b2v[t] = b2[n]; gv[t] = g[n]; btv[t] = bt[n];
    }
    #pragma unroll
    for (int t = 0; t < 8; ++t)
        #pragma unroll
        for (int r = 0; r < 4; ++r) c2[t][r] += b2v[t];

    #pragma unroll
    for (int r = 0; r < 4; ++r) {
        float s = 0.f, ss = 0.f;
        #pragma unroll
        for (int t = 0; t < 8; ++t) { float x = c2[t][r]; s += x; ss += x * x; }
        #pragma unroll
        for (int m = 1; m < 16; m <<= 1) {
            s  += __shfl_xor(s, m);
            ss += __shfl_xor(ss, m);
        }
        float mu = s * (1.f / 128.f);
        float var = ss * (1.f / 128.f) - mu * mu;
        float rstd = rsqrtf(var + 1e-5f);
        int grow = row0 + wid * 16 + ((lane >> 4) << 2) + r;
        if (grow < nrows) {
            #pragma unroll
            for (int t = 0; t < 8; ++t) {
                int n = t * 16 + colb;
                float y = (c2[t][r] - mu) * rstd * gv[t] + btv[t];
                float res = RES_BF16
                    ? bf2f(((const ushort_t*)resid)[(size_t)grow * DD + n])
                    : ((const float*)resid)[(size_t)grow * DD + n];
                float o = fmaxf(y * inv_sqrt_n, 0.f) + res;
                if (RES_BF16) {
                    outb[(size_t)grow * DD + n] = f2bf(o);
                } else {
                    outf[(size_t)grow * DD + n] = o;
                    outb[(size_t)grow * DD + n] = f2bf(o);
                }
            }
        }
    }
}

// ---------------- final edge = repeat(half_bf16, 2) -> fp32
__global__ __launch_bounds__(256) void k_expand_edge(
    const uint_t* __restrict__ half2, float2* __restrict__ out2)
{
    int t = blockIdx.x * 256 + threadIdx.x;   // NB*64 uint/float2 units
    uint_t u = half2[((t >> 7) << 6) | (t & 63)];
    out2[t] = make_float2(bf2f((ushort_t)(u & 0xffff)), bf2f((ushort_t)(u >> 16)));
}

// ---------------- graph = node.mean(axis=0)
__global__ __launch_bounds__(256) void k_graph_mean(
    const float* __restrict__ node, float* __restrict__ graph)
{
    int tid = threadIdx.x;
    int c = tid & 127, h = tid >> 7;
    const int rpb = 250;
    int r0 = blockIdx.x * rpb;
    float s = 0.f;
    for (int r = r0 + h; r < r0 + rpb; r += 2) s += node[(size_t)r * DD + c];
    __shared__ float sS[256];
    sS[tid] = s;
    __syncthreads();
    if (tid < 128) atomicAdd(&graph[c], (sS[tid] + sS[tid + 128]) * (1.f / 30000.f));
}

extern "C" void kernel_launch(void* const* d_in, const int* in_sizes, int n_in,
                              void* d_out, int out_size, void* d_ws, size_t ws_size,
                              hipStream_t stream)
{
    const int*   atom_cat         = (const int*)d_in[0];
    const int*   bond_cat         = (const int*)d_in[1];
    const float* bond_float       = (const float*)d_in[2];
    const float* angle_float      = (const float*)d_in[3];
    const int*   ab_src           = (const int*)d_in[4];
    const int*   ab_dst           = (const int*)d_in[5];
    const int*   ba_src           = (const int*)d_in[6];
    const int*   ba_dst           = (const int*)d_in[7];
    const float* atom_emb         = (const float*)d_in[8];
    const float* bond_emb_init    = (const float*)d_in[9];
    const float* bond_rbf_w_init  = (const float*)d_in[10];
    const float* bond_rbf_b_init  = (const float*)d_in[11];
    const float* layer_bond_emb   = (const float*)d_in[12];
    const float* layer_bond_rbf_w = (const float*)d_in[13];
    const float* layer_bond_rbf_b = (const float*)d_in[14];
    const float* layer_angle_rbf_w= (const float*)d_in[15];
    const float* layer_angle_rbf_b= (const float*)d_in[16];
    const float* ab_w1 = (const float*)d_in[17];
    const float* ab_b1 = (const float*)d_in[18];
    const float* ab_w2 = (const float*)d_in[19];
    const float* ab_b2 = (const float*)d_in[20];
    const float* ab_g  = (const float*)d_in[21];
    const float* ab_bt = (const float*)d_in[22];
    const float* ba_w1 = (const float*)d_in[23];
    const float* ba_b1 = (const float*)d_in[24];
    const float* ba_w2 = (const float*)d_in[25];
    const float* ba_b2 = (const float*)d_in[26];
    const float* ba_g  = (const float*)d_in[27];
    const float* ba_bt = (const float*)d_in[28];

    float* node     = (float*)d_out;                  // NA*DD
    float* edge_out = node + (size_t)NA * DD;         // NB*DD
    float* graph    = edge_out + (size_t)NB * DD;     // DD

    // ---- ws layout (bf16 buffers first, 16B-aligned blocks)
    ushort_t* agg_ab   = (ushort_t*)d_ws;                    // 30000*128
    ushort_t* node_bf  = agg_ab + (size_t)NA * DD;           // 30000*128
    ushort_t* Aext     = node_bf + (size_t)NA * DD;          // 50000*128
    ushort_t* bemb     = Aext + (size_t)NHALF * DD;          // 50000*128
    ushort_t* half_bf  = bemb + (size_t)NHALF * DD;          // 50000*128
    ushort_t* einit    = bemb;                               // aliases bemb+half_bf (NB*128)
    float*    W1ext    = (float*)(half_bf + (size_t)NHALF * DD);  // 8*128*256 f32
    ushort_t* wp_w1_ab = (ushort_t*)(W1ext + 8 * DD * HH);   // 8*32768
    ushort_t* wp_w1_ba = wp_w1_ab + 8 * 32768;               // 8*32768
    ushort_t* wp_w2    = wp_w1_ba + 8 * 32768;               // 16*32768
    int*      cur_ab   = (int*)(wp_w2 + 16 * 32768);         // 30000
    int*      cur_ba   = cur_ab + NA;                        // 50000
    int*      rp_ab    = cur_ba + NHALF;                     // 30001
    int*      rp_ba    = rp_ab + NA + 1;                     // 50001
    int*      psrc_ab  = rp_ba + NHALF + 1;                  // 100000
    int*      peid_ab  = psrc_ab + NB;                       // 100000
    int*      psrc_ba  = peid_ab + NB;                       // 200000
    float*    pang     = (float*)(psrc_ba + NANG);           // 200000

    const float isn_a = (float)(1.0 / sqrt(30000.0));
    const float isn_h = (float)(1.0 / sqrt(50000.0));

    // ---- CSR build (graphs static across layers)
    hipMemsetAsync(cur_ab, 0, (size_t)(NA + NHALF) * sizeof(int), stream);
    k_hist2<<<(NB + NANG + 255) / 256, 256, 0, stream>>>(ab_dst, cur_ab, ba_dst, cur_ba);
    k_scan<<<2, 1024, 0, stream>>>(cur_ab, rp_ab, cur_ba, rp_ba);
    k_fill_ab<<<(NB + 255) / 256, 256, 0, stream>>>(ab_src, ab_dst, cur_ab, psrc_ab, peid_ab);
    k_fill_ba<<<(NANG + 255) / 256, 256, 0, stream>>>(ba_src, ba_dst, angle_float, cur_ba, psrc_ba, pang);

    // ---- layer-invariant ba feature matrix + folded weights
    k_feat_ext<<<NHALF / 2, 256, 0, stream>>>(rp_ba, psrc_ba, pang, bond_float, bond_cat, Aext);
    k_w1ext<<<1024, 256, 0, stream>>>(ba_w1, layer_bond_emb, layer_bond_rbf_w,
        layer_bond_rbf_b, layer_angle_rbf_w, layer_angle_rbf_b, W1ext);
    k_pack_w1<<<128, 256, 0, stream>>>(ab_w1, wp_w1_ab);
    k_pack_w1<<<128, 256, 0, stream>>>(W1ext, wp_w1_ba);
    k_pack_w2<<<256, 256, 0, stream>>>(ab_w2, ba_w2, wp_w2);

    // ---- node init + layer-0 full-bond edge features (einit aliases bemb+half_bf)
    k_node_init<<<NA / 2, 256, 0, stream>>>(atom_cat, atom_emb, node, node_bf);
    k_bond_feat<<<NB / 2, 256, 0, stream>>>(bond_cat, bond_float, bond_emb_init,
        bond_rbf_w_init, bond_rbf_b_init, einit, 1);

    for (int l = 0; l < LL; ++l) {
        const ushort_t* ab_w1p = wp_w1_ab + (size_t)l * 32768;
        const ushort_t* ba_w1p = wp_w1_ba + (size_t)l * 32768;
        const ushort_t* ab_w2p = wp_w2 + (size_t)l * 32768;
        const ushort_t* ba_w2p = wp_w2 + (size_t)(8 + l) * 32768;

        if (l == 0)
            k_gather_ab<true><<<NA / 4, 256, 0, stream>>>(
                (const uint_t*)node_bf, (const uint_t*)einit, rp_ab, psrc_ab, peid_ab, (uint_t*)agg_ab);
        else
            k_gather_ab<false><<<NA / 4, 256, 0, stream>>>(
                (const uint_t*)node_bf, (const uint_t*)half_bf, rp_ab, psrc_ab, peid_ab, (uint_t*)agg_ab);

        k_mlp_mfma<false><<<(NA + MT - 1) / MT, 256, 0, stream>>>(
            agg_ab, node, ab_w1p, ab_b1 + l * HH, ab_w2p, ab_b2 + l * DD,
            ab_g + l * DD, ab_bt + l * DD, node, node_bf, isn_a, NA);

        k_bond_feat<<<NHALF / 2, 256, 0, stream>>>(bond_cat, bond_float,
            layer_bond_emb + (size_t)l * 3 * 16 * DD,
            layer_bond_rbf_w + (size_t)l * 20 * DD,
            layer_bond_rbf_b + l * DD, bemb, 2);

        k_mlp_mfma<true><<<(NHALF + MT - 1) / MT, 256, 0, stream>>>(
            Aext, bemb, ba_w1p, ba_b1 + l * HH, ba_w2p, ba_b2 + l * DD,
            ba_g + l * DD, ba_bt + l * DD, nullptr, half_bf, isn_h, NHALF);
    }

    k_expand_edge<<<(NB * 64) / 256, 256, 0, stream>>>((const uint_t*)half_bf, (float2*)edge_out);

    hipMemsetAsync(graph, 0, DD * sizeof(float), stream);
    k_graph_mean<<<120, 256, 0, stream>>>(node, graph);
}

// Round 5
// 1109.660 us; speedup vs baseline: 3.4849x; 1.0565x over previous
//
#include <hip/hip_runtime.h>
#include <math.h>

#define NA 30000
#define NB 100000
#define NHALF 50000
#define NANG 200000
#define DD 128
#define HH 256
#define LL 8

typedef unsigned short ushort_t;
typedef unsigned int uint_t;
typedef short s16x8 __attribute__((ext_vector_type(8)));
typedef float f32x4 __attribute__((ext_vector_type(4)));

__device__ __forceinline__ ushort_t f2bf(float x) {
    unsigned int u = __builtin_bit_cast(unsigned int, x);
    u += 0x7fff + ((u >> 16) & 1);
    return (ushort_t)(u >> 16);
}
__device__ __forceinline__ float bf2f(ushort_t b) {
    unsigned int u = ((unsigned int)b) << 16;
    return __builtin_bit_cast(float, u);
}

// ---------------- node init (fp32 + bf16 shadow)
__global__ __launch_bounds__(256) void k_node_init(
    const int* __restrict__ cat, const float* __restrict__ emb,
    float* __restrict__ node, ushort_t* __restrict__ node_bf)
{
    int tid = threadIdx.x;
    int r = blockIdx.x * 2 + (tid >> 7);
    int c = tid & 127;
    const int* cr = cat + r * 9;
    float v = 0.f;
    #pragma unroll
    for (int i = 0; i < 9; ++i) v += emb[((i << 6) + cr[i]) * DD + c];
    node[(size_t)r * DD + c] = v;
    node_bf[(size_t)r * DD + c] = f2bf(v);
}

// ================= CSR build =================
__global__ __launch_bounds__(256) void k_hist2(
    const int* __restrict__ ab_dst, int* __restrict__ cur_ab,
    const int* __restrict__ ba_dst, int* __restrict__ cur_ba)
{
    int i = blockIdx.x * 256 + threadIdx.x;
    if (i < NB) atomicAdd(&cur_ab[ab_dst[i]], 1);
    int j = i - NB;
    if (j >= 0 && j < NANG) atomicAdd(&cur_ba[ba_dst[j]], 1);
}

__global__ __launch_bounds__(1024) void k_scan(
    int* __restrict__ cur_ab, int* __restrict__ rp_ab,
    int* __restrict__ cur_ba, int* __restrict__ rp_ba)
{
    int N; int* cur; int* rp;
    if (blockIdx.x == 0) { cur = cur_ab; rp = rp_ab; N = NA; }
    else                 { cur = cur_ba; rp = rp_ba; N = NHALF; }
    __shared__ int sw[16];
    __shared__ int scarry;
    int tid = threadIdx.x;
    int wid = tid >> 6, lane = tid & 63;
    if (tid == 0) scarry = 0;
    __syncthreads();
    for (int base = 0; base < N; base += 1024) {
        int idx = base + tid;
        int x = (idx < N) ? cur[idx] : 0;
        int v = x;
        #pragma unroll
        for (int off = 1; off < 64; off <<= 1) {
            int t = __shfl_up(v, off);
            if (lane >= off) v += t;
        }
        if (lane == 63) sw[wid] = v;
        __syncthreads();
        if (wid == 0) {
            int wv = (lane < 16) ? sw[lane] : 0;
            #pragma unroll
            for (int off = 1; off < 16; off <<= 1) {
                int t = __shfl_up(wv, off);
                if (lane >= off) wv += t;
            }
            if (lane < 16) sw[lane] = wv;
        }
        __syncthreads();
        int wpre = (wid > 0) ? sw[wid - 1] : 0;
        int carry = scarry;
        int ex = carry + wpre + v - x;
        if (idx < N) { rp[idx] = ex; cur[idx] = ex; }
        __syncthreads();
        if (tid == 1023) scarry = carry + sw[15];
        __syncthreads();
    }
    if (tid == 0) rp[N] = scarry;
}

__global__ __launch_bounds__(256) void k_fill_ab(
    const int* __restrict__ src, const int* __restrict__ dst,
    int* __restrict__ cur, int* __restrict__ psrc, int* __restrict__ peid)
{
    int i = blockIdx.x * 256 + threadIdx.x;
    if (i < NB) {
        int p = atomicAdd(&cur[dst[i]], 1);
        psrc[p] = src[i];
        peid[p] = i;
    }
}

__global__ __launch_bounds__(256) void k_fill_ba(
    const int* __restrict__ src, const int* __restrict__ dst,
    const float* __restrict__ ang,
    int* __restrict__ cur, int* __restrict__ psrc, float* __restrict__ pang)
{
    int i = blockIdx.x * 256 + threadIdx.x;
    if (i < NANG) {
        int p = atomicAdd(&cur[dst[i]], 1);
        psrc[p] = src[i];
        pang[p] = ang[i];
    }
}

// ================= feature builders (A-frag tiled output) =================
// ba: Aext_tiled (K=128 agg feats: hist48|Rb20|Rang32|deg@100) + F_tiled (K=96 basis)
__global__ __launch_bounds__(256) void k_feat_ba(
    const int* __restrict__ rp, const int* __restrict__ psrc,
    const float* __restrict__ pang, const float* __restrict__ bfloat,
    const int* __restrict__ bcat,
    ushort_t* __restrict__ aext_t, ushort_t* __restrict__ f_t)
{
    __shared__ float sf[4][16][132];
    int tid = threadIdx.x, wid = tid >> 6, lane = tid & 63;
    int g0 = blockIdx.x * 64 + wid * 16;
    for (int r = 0; r < 16; ++r) {
        int n = g0 + r;
        float v0 = 0.f, v1 = 0.f;
        if (n < NHALF) {
            int p0 = rp[n], p1 = rp[n + 1];
            for (int pb = p0; pb < p1; pb += 64) {
                int cnt = min(p1 - pb, 64);
                int cp = 0; float bv = 0.f, av = 0.f;
                if (lane < cnt) {
                    int s = psrc[pb + lane];
                    cp = (bcat[6 * s] & 15) | ((bcat[6 * s + 1] & 15) << 4) | ((bcat[6 * s + 2] & 15) << 8);
                    bv = bfloat[2 * s];
                    av = pang[pb + lane];
                }
                for (int i = 0; i < cnt; ++i) {
                    int cpi = __shfl(cp, i);
                    float bvi = __shfl(bv, i), avi = __shfl(av, i);
                    if (lane < 48) {
                        v0 += (((cpi >> ((lane >> 4) << 2)) & 15) == (lane & 15)) ? 1.f : 0.f;
                    } else {
                        float d = bvi - 0.1f * (float)(lane - 48);
                        v0 += expf(-10.f * d * d);
                    }
                    if (lane < 4) { float d = bvi - 0.1f * (float)(lane + 16); v1 += expf(-10.f * d * d); }
                    else if (lane < 36) { float d = avi - 0.1f * (float)(lane - 4); v1 += expf(-10.f * d * d); }
                    else if (lane == 36) v1 += 1.f;
                }
            }
        }
        sf[wid][r][lane] = v0;
        sf[wid][r][64 + lane] = v1;
    }
    __syncthreads();
    {
        int ar = lane & 15, aq = (lane >> 4) << 3;
        #pragma unroll
        for (int s = 0; s < 4; ++s) {
            const float* src = &sf[wid][ar][s * 32 + aq];
            uint_t pk[4];
            #pragma unroll
            for (int j = 0; j < 4; ++j)
                pk[j] = (uint_t)f2bf(src[2 * j]) | ((uint_t)f2bf(src[2 * j + 1]) << 16);
            *(uint4*)(aext_t + ((((size_t)blockIdx.x * 4 + wid) * 4 + s) * 64 + lane) * 8) =
                make_uint4(pk[0], pk[1], pk[2], pk[3]);
        }
    }
    __syncthreads();
    for (int r = 0; r < 16; ++r) {
        int n = g0 + r;
        float v0 = 0.f, v1 = 0.f;
        if (n < NHALF) {
            if (lane < 48) {
                v0 = (bcat[6 * n + (lane >> 4)] == (lane & 15)) ? 1.f : 0.f;
            } else {
                float d = bfloat[2 * n] - 0.1f * (float)(lane - 48);
                v0 = expf(-10.f * d * d);
            }
            if (lane < 4) { float d = bfloat[2 * n] - 0.1f * (float)(lane + 16); v1 = expf(-10.f * d * d); }
            else if (lane == 4) v1 = 1.f;
        }
        sf[wid][r][lane] = v0;
        sf[wid][r][64 + lane] = v1;
    }
    __syncthreads();
    {
        int ar = lane & 15, aq = (lane >> 4) << 3;
        #pragma unroll
        for (int s = 0; s < 3; ++s) {
            const float* src = &sf[wid][ar][s * 32 + aq];
            uint_t pk[4];
            #pragma unroll
            for (int j = 0; j < 4; ++j)
                pk[j] = (uint_t)f2bf(src[2 * j]) | ((uint_t)f2bf(src[2 * j + 1]) << 16);
            *(uint4*)(f_t + ((((size_t)blockIdx.x * 4 + wid) * 3 + s) * 64 + lane) * 8) =
                make_uint4(pk[0], pk[1], pk[2], pk[3]);
        }
    }
}

// ab: Fab_tiled (K=96 agg feats over incoming bonds: hist48|Rb20|deg@68)
__global__ __launch_bounds__(256) void k_feat_ab(
    const int* __restrict__ rp, const int* __restrict__ peid,
    const float* __restrict__ bfloat, const int* __restrict__ bcat,
    ushort_t* __restrict__ fab_t)
{
    __shared__ float sf[4][16][132];
    int tid = threadIdx.x, wid = tid >> 6, lane = tid & 63;
    int g0 = blockIdx.x * 64 + wid * 16;
    for (int r = 0; r < 16; ++r) {
        int n = g0 + r;
        float v0 = 0.f, v1 = 0.f;
        if (n < NA) {
            int p0 = rp[n], p1 = rp[n + 1];
            for (int pb = p0; pb < p1; pb += 64) {
                int cnt = min(p1 - pb, 64);
                int cp = 0; float bv = 0.f;
                if (lane < cnt) {
                    int e = peid[pb + lane];
                    cp = (bcat[3 * e] & 15) | ((bcat[3 * e + 1] & 15) << 4) | ((bcat[3 * e + 2] & 15) << 8);
                    bv = bfloat[e];
                }
                for (int i = 0; i < cnt; ++i) {
                    int cpi = __shfl(cp, i);
                    float bvi = __shfl(bv, i);
                    if (lane < 48) {
                        v0 += (((cpi >> ((lane >> 4) << 2)) & 15) == (lane & 15)) ? 1.f : 0.f;
                    } else {
                        float d = bvi - 0.1f * (float)(lane - 48);
                        v0 += expf(-10.f * d * d);
                    }
                    if (lane < 4) { float d = bvi - 0.1f * (float)(lane + 16); v1 += expf(-10.f * d * d); }
                    else if (lane == 4) v1 += 1.f;
                }
            }
        }
        sf[wid][r][lane] = v0;
        sf[wid][r][64 + lane] = v1;
    }
    __syncthreads();
    int ar = lane & 15, aq = (lane >> 4) << 3;
    #pragma unroll
    for (int s = 0; s < 3; ++s) {
        const float* src = &sf[wid][ar][s * 32 + aq];
        uint_t pk[4];
        #pragma unroll
        for (int j = 0; j < 4; ++j)
            pk[j] = (uint_t)f2bf(src[2 * j]) | ((uint_t)f2bf(src[2 * j + 1]) << 16);
        *(uint4*)(fab_t + ((((size_t)blockIdx.x * 4 + wid) * 3 + s) * 64 + lane) * 8) =
            make_uint4(pk[0], pk[1], pk[2], pk[3]);
    }
}

// ================= weight folds (fp32) =================
// W1ext[l][128][256] for ba GEMM1; W1ab0x[96][256] = G0 @ ab_w1[0]
__global__ __launch_bounds__(256) void k_fold(
    const float* __restrict__ ba_w1, const float* __restrict__ lbemb,
    const float* __restrict__ rwb, const float* __restrict__ rbvb,
    const float* __restrict__ rwa, const float* __restrict__ rbva,
    const float* __restrict__ ab_w1, const float* __restrict__ bei,
    const float* __restrict__ brw, const float* __restrict__ brb,
    float* __restrict__ W1ext, float* __restrict__ W1ab0x)
{
    int f = blockIdx.x * 256 + threadIdx.x;
    if (f < 262144) {
        int n = f & 255, k = (f >> 8) & 127, l = f >> 15;
        float v = 0.f;
        if (k <= 100) {
            const float* w1 = ba_w1 + (size_t)l * 32768 + n;
            if (k == 100) {
                const float* r1 = rbvb + (size_t)l * 128;
                const float* r2 = rbva + (size_t)l * 128;
                for (int c = 0; c < 128; ++c) v += (r1[c] + r2[c]) * w1[(size_t)c * 256];
            } else {
                const float* row = (k < 48) ? lbemb + ((size_t)l * 48 + k) * 128
                                 : (k < 68) ? rwb + ((size_t)l * 20 + (k - 48)) * 128
                                            : rwa + ((size_t)l * 32 + (k - 68)) * 128;
                for (int c = 0; c < 128; ++c) v += row[c] * w1[(size_t)c * 256];
            }
        }
        W1ext[f] = v;
    } else if (f < 286720) {
        int f2 = f - 262144;
        int n = f2 & 255, k = f2 >> 8;   // k < 96
        float v = 0.f;
        if (k <= 68) {
            const float* w1 = ab_w1 + n;  // layer 0
            const float* row = (k < 48) ? bei + (size_t)k * 128
                             : (k < 68) ? brw + (size_t)(k - 48) * 128
                                        : brb;
            for (int c = 0; c < 128; ++c) v += row[c] * w1[(size_t)c * 256];
        }
        W1ab0x[f2] = v;
    }
}

// ================= pack everything into B-frag order =================
// regions (frag units): [0,7168) W1ab0 K224; [7168,35840) ab_w1 l1-7;
// [35840,68608) W1ext_ba; [68608,134144) w2 ab+ba; [134144,146432) G
__global__ __launch_bounds__(256) void k_pack(
    const float* __restrict__ ab_w1, const float* __restrict__ W1ab0x,
    const float* __restrict__ W1ext, const float* __restrict__ ab_w2,
    const float* __restrict__ ba_w2, const float* __restrict__ lbemb,
    const float* __restrict__ rwb, const float* __restrict__ rbvb,
    ushort_t* __restrict__ wp)
{
    int f = blockIdx.x * 256 + threadIdx.x;
    if (f >= 146432) return;
    int lane = f & 63;
    int k0 = 0, n = 0, N = 256;
    const float* W = nullptr;
    float vals[8];
    if (f < 7168) {
        int ts = f >> 6; int s = ts % 7, t = ts / 7;
        k0 = s * 32 + ((lane >> 4) << 3); n = t * 16 + (lane & 15); N = 256;
        if (k0 < 128) W = ab_w1;
        else { W = W1ab0x; k0 -= 128; }
    } else if (f < 35840) {
        int f2 = f - 7168; int ts = f2 >> 6;
        int s = ts & 3, t = (ts >> 2) & 15, l = (ts >> 6) + 1;
        W = ab_w1 + (size_t)l * 32768; N = 256;
        k0 = s * 32 + ((lane >> 4) << 3); n = t * 16 + (lane & 15);
    } else if (f < 68608) {
        int f2 = f - 35840; int ts = f2 >> 6;
        int s = ts & 3, t = (ts >> 2) & 15, l = ts >> 6;
        W = W1ext + (size_t)l * 32768; N = 256;
        k0 = s * 32 + ((lane >> 4) << 3); n = t * 16 + (lane & 15);
    } else if (f < 134144) {
        int f2 = f - 68608; int ts = f2 >> 6;
        int s = ts & 7, t = (ts >> 3) & 7, l = (ts >> 6) & 7, grp = ts >> 9;
        W = (grp ? ba_w2 : ab_w2) + (size_t)l * 32768; N = 128;
        k0 = s * 32 + ((lane >> 4) << 3); n = t * 16 + (lane & 15);
    } else {
        int f2 = f - 134144; int ts = f2 >> 6;
        int s = ts % 3, t = (ts / 3) & 7, l = ts / 24;
        N = 128; k0 = s * 32 + ((lane >> 4) << 3); n = t * 16 + (lane & 15);
        #pragma unroll
        for (int j = 0; j < 8; ++j) {
            int k = k0 + j; float v;
            if (k < 48) v = lbemb[(size_t)l * 6144 + (size_t)k * 128 + n];
            else if (k < 68) v = rwb[(size_t)l * 2560 + (size_t)(k - 48) * 128 + n];
            else if (k == 68) v = rbvb[(size_t)l * 128 + n];
            else v = 0.f;
            vals[j] = v;
        }
    }
    if (W) {
        #pragma unroll
        for (int j = 0; j < 8; ++j) vals[j] = W[(size_t)(k0 + j) * N + n];
    }
    uint_t pk[4];
    #pragma unroll
    for (int j = 0; j < 4; ++j)
        pk[j] = (uint_t)f2bf(vals[2 * j]) | ((uint_t)f2bf(vals[2 * j + 1]) << 16);
    *(uint4*)(wp + (size_t)f * 8) = make_uint4(pk[0], pk[1], pk[2], pk[3]);
}

// ================= fused gather + MLP (ab path) =================
template<int KS, bool L0>
__global__ __launch_bounds__(256) void k_mlp_ab(
    const uint_t* __restrict__ node2, const uint_t* __restrict__ half2,
    const ushort_t* __restrict__ fab_t,
    const int* __restrict__ rp, const int* __restrict__ psrc,
    const int* __restrict__ peid,
    const ushort_t* __restrict__ w1p, const float* __restrict__ b1,
    const ushort_t* __restrict__ w2p, const float* __restrict__ b2,
    const float* __restrict__ g, const float* __restrict__ bt,
    const float* __restrict__ resid, float* __restrict__ outf,
    ushort_t* __restrict__ outb, float inv_sqrt_n)
{
    __shared__ ushort_t sA[4][16 * 136];
    __shared__ ushort_t sC1[4][16 * 264];
    int tid = threadIdx.x, wid = tid >> 6, lane = tid & 63;
    int g0 = blockIdx.x * 64 + wid * 16;

    // wave-private gather: 16 rows, lane holds cols (2lane, 2lane+1)
    for (int r = 0; r < 16; ++r) {
        int n = g0 + r;
        float v0 = 0.f, v1 = 0.f;
        if (n < NA) {
            int p0 = rp[n], p1 = rp[n + 1];
            for (int p = p0; p < p1; ++p) {
                int s = psrc[p];
                uint_t a = node2[(size_t)s * 64 + lane];
                v0 += bf2f((ushort_t)(a & 0xffff));
                v1 += bf2f((ushort_t)(a >> 16));
                if (!L0) {
                    int e = peid[p];
                    uint_t b = half2[(size_t)(e >> 1) * 64 + lane];
                    v0 += bf2f((ushort_t)(b & 0xffff));
                    v1 += bf2f((ushort_t)(b >> 16));
                }
            }
        }
        *(uint_t*)&sA[wid][r * 136 + lane * 2] = (uint_t)f2bf(v0) | ((uint_t)f2bf(v1) << 16);
    }
    __syncthreads();

    int arow = lane & 15, aq = (lane >> 4) << 3;
    s16x8 af[KS];
    #pragma unroll
    for (int s = 0; s < 4; ++s) af[s] = *(const s16x8*)&sA[wid][arow * 136 + s * 32 + aq];
    if (L0) {
        #pragma unroll
        for (int s = 0; s < 3; ++s)
            af[4 + s] = *(const s16x8*)(fab_t + ((((size_t)blockIdx.x * 4 + wid) * 3 + s) * 64 + lane) * 8);
    }

    // GEMM1 (B-frags direct from global, no barriers)
    for (int t = 0; t < 16; ++t) {
        f32x4 acc = {0.f, 0.f, 0.f, 0.f};
        #pragma unroll
        for (int s = 0; s < KS; ++s) {
            s16x8 bf = *(const s16x8*)(w1p + ((size_t)(t * KS + s) * 64 + lane) * 8);
            acc = __builtin_amdgcn_mfma_f32_16x16x32_bf16(af[s], bf, acc, 0, 0, 0);
        }
        int n = t * 16 + (lane & 15);
        float b1v = b1[n];
        int r0 = (lane >> 4) << 2;
        #pragma unroll
        for (int r = 0; r < 4; ++r)
            sC1[wid][(r0 + r) * 264 + n] = f2bf(fmaxf(acc[r] + b1v, 0.f));
    }
    __syncthreads();

    s16x8 a2[8];
    #pragma unroll
    for (int s = 0; s < 8; ++s) a2[s] = *(const s16x8*)&sC1[wid][arow * 264 + s * 32 + aq];
    f32x4 c2[8];
    for (int t = 0; t < 8; ++t) {
        f32x4 acc = {0.f, 0.f, 0.f, 0.f};
        #pragma unroll
        for (int s = 0; s < 8; ++s) {
            s16x8 bf = *(const s16x8*)(w2p + ((size_t)(t * 8 + s) * 64 + lane) * 8);
            acc = __builtin_amdgcn_mfma_f32_16x16x32_bf16(a2[s], bf, acc, 0, 0, 0);
        }
        c2[t] = acc;
    }

    // epilogue
    int colb = lane & 15;
    float b2v[8], gv[8], btv[8];
    #pragma unroll
    for (int t = 0; t < 8; ++t) {
        int n = t * 16 + colb;
        b2v[t] = b2[n]; gv[t] = g[n]; btv[t] = bt[n];
    }
    #pragma unroll
    for (int t = 0; t < 8; ++t)
        #pragma unroll
        for (int r = 0; r < 4; ++r) c2[t][r] += b2v[t];

    int r0 = (lane >> 4) << 2;
    #pragma unroll
    for (int r = 0; r < 4; ++r) {
        float s = 0.f, ss = 0.f;
        #pragma unroll
        for (int t = 0; t < 8; ++t) { float x = c2[t][r]; s += x; ss += x * x; }
        #pragma unroll
        for (int m = 1; m < 16; m <<= 1) {
            s  += __shfl_xor(s, m);
            ss += __shfl_xor(ss, m);
        }
        float mu = s * (1.f / 128.f);
        float var = ss * (1.f / 128.f) - mu * mu;
        float rstd = rsqrtf(var + 1e-5f);
        int grow = g0 + r0 + r;
        if (grow < NA) {
            #pragma unroll
            for (int t = 0; t < 8; ++t) {
                int n = t * 16 + colb;
                float y = (c2[t][r] - mu) * rstd * gv[t] + btv[t];
                float o = fmaxf(y * inv_sqrt_n, 0.f) + resid[(size_t)grow * DD + n];
                outf[(size_t)grow * DD + n] = o;
                outb[(size_t)grow * DD + n] = f2bf(o);
            }
        }
    }
}

// ================= MLP (ba path): Aext GEMM1 + GEMM2 + residual GEMM3 =================
template<bool LAST>
__global__ __launch_bounds__(256) void k_mlp_ba(
    const ushort_t* __restrict__ aext_t, const ushort_t* __restrict__ f_t,
    const ushort_t* __restrict__ w1p, const float* __restrict__ b1,
    const ushort_t* __restrict__ w2p, const float* __restrict__ b2,
    const ushort_t* __restrict__ gp,
    const float* __restrict__ g, const float* __restrict__ bt,
    ushort_t* __restrict__ outb, float* __restrict__ edge_out,
    float inv_sqrt_n)
{
    __shared__ ushort_t sC1[4][16 * 264];
    int tid = threadIdx.x, wid = tid >> 6, lane = tid & 63;
    int arow = lane & 15, aq = (lane >> 4) << 3;

    s16x8 af[4];
    #pragma unroll
    for (int s = 0; s < 4; ++s)
        af[s] = *(const s16x8*)(aext_t + ((((size_t)blockIdx.x * 4 + wid) * 4 + s) * 64 + lane) * 8);

    for (int t = 0; t < 16; ++t) {
        f32x4 acc = {0.f, 0.f, 0.f, 0.f};
        #pragma unroll
        for (int s = 0; s < 4; ++s) {
            s16x8 bf = *(const s16x8*)(w1p + ((size_t)(t * 4 + s) * 64 + lane) * 8);
            acc = __builtin_amdgcn_mfma_f32_16x16x32_bf16(af[s], bf, acc, 0, 0, 0);
        }
        int n = t * 16 + (lane & 15);
        float b1v = b1[n];
        int r0 = (lane >> 4) << 2;
        #pragma unroll
        for (int r = 0; r < 4; ++r)
            sC1[wid][(r0 + r) * 264 + n] = f2bf(fmaxf(acc[r] + b1v, 0.f));
    }
    __syncthreads();

    s16x8 a2[8];
    #pragma unroll
    for (int s = 0; s < 8; ++s) a2[s] = *(const s16x8*)&sC1[wid][arow * 264 + s * 32 + aq];
    f32x4 c2[8];
    for (int t = 0; t < 8; ++t) {
        f32x4 acc = {0.f, 0.f, 0.f, 0.f};
        #pragma unroll
        for (int s = 0; s < 8; ++s) {
            s16x8 bf = *(const s16x8*)(w2p + ((size_t)(t * 8 + s) * 64 + lane) * 8);
            acc = __builtin_amdgcn_mfma_f32_16x16x32_bf16(a2[s], bf, acc, 0, 0, 0);
        }
        c2[t] = acc;
    }

    s16x8 af3[3];
    #pragma unroll
    for (int s = 0; s < 3; ++s)
        af3[s] = *(const s16x8*)(f_t + ((((size_t)blockIdx.x * 4 + wid) * 3 + s) * 64 + lane) * 8);

    // epilogue
    int colb = lane & 15;
    {
        float b2v[8];
        #pragma unroll
        for (int t = 0; t < 8; ++t) b2v[t] = b2[t * 16 + colb];
        #pragma unroll
        for (int t = 0; t < 8; ++t)
            #pragma unroll
            for (int r = 0; r < 4; ++r) c2[t][r] += b2v[t];
    }
    float mu4[4], rs4[4];
    #pragma unroll
    for (int r = 0; r < 4; ++r) {
        float s = 0.f, ss = 0.f;
        #pragma unroll
        for (int t = 0; t < 8; ++t) { float x = c2[t][r]; s += x; ss += x * x; }
        #pragma unroll
        for (int m = 1; m < 16; m <<= 1) {
            s  += __shfl_xor(s, m);
            ss += __shfl_xor(ss, m);
        }
        float mu = s * (1.f / 128.f);
        float var = ss * (1.f / 128.f) - mu * mu;
        mu4[r] = mu;
        rs4[r] = rsqrtf(var + 1e-5f);
    }
    int r0 = (lane >> 4) << 2;
    int growb = blockIdx.x * 64 + wid * 16 + r0;
    #pragma unroll
    for (int t = 0; t < 8; ++t) {
        f32x4 racc = {0.f, 0.f, 0.f, 0.f};
        #pragma unroll
        for (int s = 0; s < 3; ++s) {
            s16x8 bf = *(const s16x8*)(gp + ((size_t)(t * 3 + s) * 64 + lane) * 8);
            racc = __builtin_amdgcn_mfma_f32_16x16x32_bf16(af3[s], bf, racc, 0, 0, 0);
        }
        int n = t * 16 + colb;
        float gv = g[n], btv = bt[n];
        #pragma unroll
        for (int r = 0; r < 4; ++r) {
            int grow = growb + r;
            if (grow < NHALF) {
                float y = (c2[t][r] - mu4[r]) * rs4[r] * gv + btv;
                float o = fmaxf(y * inv_sqrt_n, 0.f) + racc[r];
                if (!LAST) {
                    outb[(size_t)grow * DD + n] = f2bf(o);
                } else {
                    edge_out[(size_t)(2 * grow) * DD + n] = o;
                    edge_out[(size_t)(2 * grow + 1) * DD + n] = o;
                }
            }
        }
    }
}

// ---------------- graph = node.mean(axis=0)
__global__ __launch_bounds__(256) void k_graph_mean(
    const float* __restrict__ node, float* __restrict__ graph)
{
    int tid = threadIdx.x;
    int c = tid & 127, h = tid >> 7;
    const int rpb = 250;
    int r0 = blockIdx.x * rpb;
    float s = 0.f;
    for (int r = r0 + h; r < r0 + rpb; r += 2) s += node[(size_t)r * DD + c];
    __shared__ float sS[256];
    sS[tid] = s;
    __syncthreads();
    if (tid < 128) atomicAdd(&graph[c], (sS[tid] + sS[tid + 128]) * (1.f / 30000.f));
}

extern "C" void kernel_launch(void* const* d_in, const int* in_sizes, int n_in,
                              void* d_out, int out_size, void* d_ws, size_t ws_size,
                              hipStream_t stream)
{
    const int*   atom_cat         = (const int*)d_in[0];
    const int*   bond_cat         = (const int*)d_in[1];
    const float* bond_float       = (const float*)d_in[2];
    const float* angle_float      = (const float*)d_in[3];
    const int*   ab_src           = (const int*)d_in[4];
    const int*   ab_dst           = (const int*)d_in[5];
    const int*   ba_src           = (const int*)d_in[6];
    const int*   ba_dst           = (const int*)d_in[7];
    const float* atom_emb         = (const float*)d_in[8];
    const float* bond_emb_init    = (const float*)d_in[9];
    const float* bond_rbf_w_init  = (const float*)d_in[10];
    const float* bond_rbf_b_init  = (const float*)d_in[11];
    const float* layer_bond_emb   = (const float*)d_in[12];
    const float* layer_bond_rbf_w = (const float*)d_in[13];
    const float* layer_bond_rbf_b = (const float*)d_in[14];
    const float* layer_angle_rbf_w= (const float*)d_in[15];
    const float* layer_angle_rbf_b= (const float*)d_in[16];
    const float* ab_w1 = (const float*)d_in[17];
    const float* ab_b1 = (const float*)d_in[18];
    const float* ab_w2 = (const float*)d_in[19];
    const float* ab_b2 = (const float*)d_in[20];
    const float* ab_g  = (const float*)d_in[21];
    const float* ab_bt = (const float*)d_in[22];
    const float* ba_w1 = (const float*)d_in[23];
    const float* ba_b1 = (const float*)d_in[24];
    const float* ba_w2 = (const float*)d_in[25];
    const float* ba_b2 = (const float*)d_in[26];
    const float* ba_g  = (const float*)d_in[27];
    const float* ba_bt = (const float*)d_in[28];

    float* node     = (float*)d_out;
    float* edge_out = node + (size_t)NA * DD;
    float* graph    = edge_out + (size_t)NB * DD;

    // ---- ws layout (ushort units first, 16B aligned throughout)
    ushort_t* base   = (ushort_t*)d_ws;
    ushort_t* nbf0   = base;                                   // NA*DD
    ushort_t* nbf1   = nbf0 + (size_t)NA * DD;                 // NA*DD
    ushort_t* half_bf= nbf1 + (size_t)NA * DD;                 // NHALF*DD
    ushort_t* aext_t = half_bf + (size_t)NHALF * DD;           // 782*8192 = 6406144
    ushort_t* f_t    = aext_t + (size_t)782 * 8192;            // 782*6144 = 4804608
    ushort_t* fab_t  = f_t + (size_t)782 * 6144;               // 469*6144 = 2881536
    ushort_t* wp     = fab_t + (size_t)469 * 6144;             // 146432*8 = 1171456
    float*    W1ext  = (float*)(wp + (size_t)146432 * 8);      // 262144 f32
    float*    W1ab0x = W1ext + 262144;                         // 24576 f32
    int*      cur_ab = (int*)(W1ab0x + 24576);                 // NA
    int*      cur_ba = cur_ab + NA;                            // NHALF
    int*      rp_ab  = cur_ba + NHALF;                         // NA+1
    int*      rp_ba  = rp_ab + NA + 1;                         // NHALF+1
    int*      psrc_ab= rp_ba + NHALF + 1;                      // NB
    int*      peid_ab= psrc_ab + NB;                           // NB
    int*      psrc_ba= peid_ab + NB;                           // NANG
    float*    pang   = (float*)(psrc_ba + NANG);               // NANG

    const float isn_a = (float)(1.0 / sqrt(30000.0));
    const float isn_h = (float)(1.0 / sqrt(50000.0));

    // ---- CSR build
    hipMemsetAsync(cur_ab, 0, (size_t)(NA + NHALF) * sizeof(int), stream);
    k_hist2<<<(NB + NANG + 255) / 256, 256, 0, stream>>>(ab_dst, cur_ab, ba_dst, cur_ba);
    k_scan<<<2, 1024, 0, stream>>>(cur_ab, rp_ab, cur_ba, rp_ba);
    k_fill_ab<<<(NB + 255) / 256, 256, 0, stream>>>(ab_src, ab_dst, cur_ab, psrc_ab, peid_ab);
    k_fill_ba<<<(NANG + 255) / 256, 256, 0, stream>>>(ba_src, ba_dst, angle_float, cur_ba, psrc_ba, pang);

    // ---- folds + packing + tiled feature matrices
    k_fold<<<1120, 256, 0, stream>>>(ba_w1, layer_bond_emb, layer_bond_rbf_w,
        layer_bond_rbf_b, layer_angle_rbf_w, layer_angle_rbf_b,
        ab_w1, bond_emb_init, bond_rbf_w_init, bond_rbf_b_init, W1ext, W1ab0x);
    k_pack<<<572, 256, 0, stream>>>(ab_w1, W1ab0x, W1ext, ab_w2, ba_w2,
        layer_bond_emb, layer_bond_rbf_w, layer_bond_rbf_b, wp);
    k_feat_ba<<<782, 256, 0, stream>>>(rp_ba, psrc_ba, pang, bond_float, bond_cat, aext_t, f_t);
    k_feat_ab<<<469, 256, 0, stream>>>(rp_ab, peid_ab, bond_float, bond_cat, fab_t);

    k_node_init<<<NA / 2, 256, 0, stream>>>(atom_cat, atom_emb, node, nbf0);

    ushort_t* nbf[2] = {nbf0, nbf1};
    for (int l = 0; l < LL; ++l) {
        const ushort_t* ab_w1p = l ? wp + ((size_t)7168 + (size_t)(l - 1) * 4096) * 8 : wp;
        const ushort_t* ba_w1p = wp + ((size_t)35840 + (size_t)l * 4096) * 8;
        const ushort_t* ab_w2p = wp + ((size_t)68608 + (size_t)l * 4096) * 8;
        const ushort_t* ba_w2p = wp + ((size_t)68608 + (size_t)(8 + l) * 4096) * 8;
        const ushort_t* gpl    = wp + ((size_t)134144 + (size_t)l * 1536) * 8;
        const uint_t* rd = (const uint_t*)nbf[l & 1];
        ushort_t* wr = nbf[1 - (l & 1)];

        if (l == 0)
            k_mlp_ab<7, true><<<469, 256, 0, stream>>>(
                rd, rd, fab_t, rp_ab, psrc_ab, peid_ab,
                ab_w1p, ab_b1, ab_w2p, ab_b2, ab_g, ab_bt,
                node, node, wr, isn_a);
        else
            k_mlp_ab<4, false><<<469, 256, 0, stream>>>(
                rd, (const uint_t*)half_bf, fab_t, rp_ab, psrc_ab, peid_ab,
                ab_w1p, ab_b1 + l * HH, ab_w2p, ab_b2 + l * DD,
                ab_g + l * DD, ab_bt + l * DD, node, node, wr, isn_a);

        if (l < LL - 1)
            k_mlp_ba<false><<<782, 256, 0, stream>>>(
                aext_t, f_t, ba_w1p, ba_b1 + l * HH, ba_w2p, ba_b2 + l * DD,
                gpl, ba_g + l * DD, ba_bt + l * DD, half_bf, edge_out, isn_h);
        else
            k_mlp_ba<true><<<782, 256, 0, stream>>>(
                aext_t, f_t, ba_w1p, ba_b1 + l * HH, ba_w2p, ba_b2 + l * DD,
                gpl, ba_g + l * DD, ba_bt + l * DD, half_bf, edge_out, isn_h);
    }

    hipMemsetAsync(graph, 0, DD * sizeof(float), stream);
    k_graph_mean<<<120, 256, 0, stream>>>(node, graph);
}

// Round 7
// 1005.592 us; speedup vs baseline: 3.8455x; 1.1035x over previous
//
#include <hip/hip_runtime.h>
#include <math.h>

#define NA 30000
#define NB 100000
#define NHALF 50000
#define NANG 200000
#define DD 128
#define HH 256
#define LL 8

typedef unsigned short ushort_t;
typedef unsigned int uint_t;
typedef short s16x8 __attribute__((ext_vector_type(8)));
typedef float f32x4 __attribute__((ext_vector_type(4)));

__device__ __forceinline__ ushort_t f2bf(float x) {
    unsigned int u = __builtin_bit_cast(unsigned int, x);
    u += 0x7fff + ((u >> 16) & 1);
    return (ushort_t)(u >> 16);
}
__device__ __forceinline__ float bf2f(ushort_t b) {
    unsigned int u = ((unsigned int)b) << 16;
    return __builtin_bit_cast(float, u);
}

// ---------------- node init (fp32 + bf16 shadow)
__global__ __launch_bounds__(256) void k_node_init(
    const int* __restrict__ cat, const float* __restrict__ emb,
    float* __restrict__ node, ushort_t* __restrict__ node_bf)
{
    int tid = threadIdx.x;
    int r = blockIdx.x * 2 + (tid >> 7);
    int c = tid & 127;
    const int* cr = cat + r * 9;
    float v = 0.f;
    #pragma unroll
    for (int i = 0; i < 9; ++i) v += emb[((i << 6) + cr[i]) * DD + c];
    node[(size_t)r * DD + c] = v;
    node_bf[(size_t)r * DD + c] = f2bf(v);
}

// ================= CSR build =================
__global__ __launch_bounds__(256) void k_hist2(
    const int* __restrict__ ab_dst, int* __restrict__ cur_ab,
    const int* __restrict__ ba_dst, int* __restrict__ cur_ba)
{
    int i = blockIdx.x * 256 + threadIdx.x;
    if (i < NB) atomicAdd(&cur_ab[ab_dst[i]], 1);
    int j = i - NB;
    if (j >= 0 && j < NANG) atomicAdd(&cur_ba[ba_dst[j]], 1);
}

__global__ __launch_bounds__(1024) void k_scan(
    int* __restrict__ cur_ab, int* __restrict__ rp_ab,
    int* __restrict__ cur_ba, int* __restrict__ rp_ba)
{
    int N; int* cur; int* rp;
    if (blockIdx.x == 0) { cur = cur_ab; rp = rp_ab; N = NA; }
    else                 { cur = cur_ba; rp = rp_ba; N = NHALF; }
    __shared__ int sw[16];
    __shared__ int scarry;
    int tid = threadIdx.x;
    int wid = tid >> 6, lane = tid & 63;
    if (tid == 0) scarry = 0;
    __syncthreads();
    for (int base = 0; base < N; base += 1024) {
        int idx = base + tid;
        int x = (idx < N) ? cur[idx] : 0;
        int v = x;
        #pragma unroll
        for (int off = 1; off < 64; off <<= 1) {
            int t = __shfl_up(v, off);
            if (lane >= off) v += t;
        }
        if (lane == 63) sw[wid] = v;
        __syncthreads();
        if (wid == 0) {
            int wv = (lane < 16) ? sw[lane] : 0;
            #pragma unroll
            for (int off = 1; off < 16; off <<= 1) {
                int t = __shfl_up(wv, off);
                if (lane >= off) wv += t;
            }
            if (lane < 16) sw[lane] = wv;
        }
        __syncthreads();
        int wpre = (wid > 0) ? sw[wid - 1] : 0;
        int carry = scarry;
        int ex = carry + wpre + v - x;
        if (idx < N) { rp[idx] = ex; cur[idx] = ex; }
        __syncthreads();
        if (tid == 1023) scarry = carry + sw[15];
        __syncthreads();
    }
    if (tid == 0) rp[N] = scarry;
}

__global__ __launch_bounds__(256) void k_fill_ab(
    const int* __restrict__ src, const int* __restrict__ dst,
    int* __restrict__ cur, int* __restrict__ psrc, int* __restrict__ peid)
{
    int i = blockIdx.x * 256 + threadIdx.x;
    if (i < NB) {
        int p = atomicAdd(&cur[dst[i]], 1);
        psrc[p] = src[i];
        peid[p] = i;
    }
}

__global__ __launch_bounds__(256) void k_fill_ba(
    const int* __restrict__ src, const int* __restrict__ dst,
    const float* __restrict__ ang,
    int* __restrict__ cur, int* __restrict__ psrc, float* __restrict__ pang)
{
    int i = blockIdx.x * 256 + threadIdx.x;
    if (i < NANG) {
        int p = atomicAdd(&cur[dst[i]], 1);
        psrc[p] = src[i];
        pang[p] = ang[i];
    }
}

// ================= feature builders (A-frag tiled output) — round-5 verbatim =================
__global__ __launch_bounds__(256) void k_feat_ba(
    const int* __restrict__ rp, const int* __restrict__ psrc,
    const float* __restrict__ pang, const float* __restrict__ bfloat,
    const int* __restrict__ bcat,
    ushort_t* __restrict__ aext_t, ushort_t* __restrict__ f_t)
{
    __shared__ float sf[4][16][132];
    int tid = threadIdx.x, wid = tid >> 6, lane = tid & 63;
    int g0 = blockIdx.x * 64 + wid * 16;
    for (int r = 0; r < 16; ++r) {
        int n = g0 + r;
        float v0 = 0.f, v1 = 0.f;
        if (n < NHALF) {
            int p0 = rp[n], p1 = rp[n + 1];
            for (int pb = p0; pb < p1; pb += 64) {
                int cnt = min(p1 - pb, 64);
                int cp = 0; float bv = 0.f, av = 0.f;
                if (lane < cnt) {
                    int s = psrc[pb + lane];
                    cp = (bcat[6 * s] & 15) | ((bcat[6 * s + 1] & 15) << 4) | ((bcat[6 * s + 2] & 15) << 8);
                    bv = bfloat[2 * s];
                    av = pang[pb + lane];
                }
                for (int i = 0; i < cnt; ++i) {
                    int cpi = __shfl(cp, i);
                    float bvi = __shfl(bv, i), avi = __shfl(av, i);
                    if (lane < 48) {
                        v0 += (((cpi >> ((lane >> 4) << 2)) & 15) == (lane & 15)) ? 1.f : 0.f;
                    } else {
                        float d = bvi - 0.1f * (float)(lane - 48);
                        v0 += expf(-10.f * d * d);
                    }
                    if (lane < 4) { float d = bvi - 0.1f * (float)(lane + 16); v1 += expf(-10.f * d * d); }
                    else if (lane < 36) { float d = avi - 0.1f * (float)(lane - 4); v1 += expf(-10.f * d * d); }
                    else if (lane == 36) v1 += 1.f;
                }
            }
        }
        sf[wid][r][lane] = v0;
        sf[wid][r][64 + lane] = v1;
    }
    __syncthreads();
    {
        int ar = lane & 15, aq = (lane >> 4) << 3;
        #pragma unroll
        for (int s = 0; s < 4; ++s) {
            const float* src = &sf[wid][ar][s * 32 + aq];
            uint_t pk[4];
            #pragma unroll
            for (int j = 0; j < 4; ++j)
                pk[j] = (uint_t)f2bf(src[2 * j]) | ((uint_t)f2bf(src[2 * j + 1]) << 16);
            *(uint4*)(aext_t + ((((size_t)blockIdx.x * 4 + wid) * 4 + s) * 64 + lane) * 8) =
                make_uint4(pk[0], pk[1], pk[2], pk[3]);
        }
    }
    __syncthreads();
    for (int r = 0; r < 16; ++r) {
        int n = g0 + r;
        float v0 = 0.f, v1 = 0.f;
        if (n < NHALF) {
            if (lane < 48) {
                v0 = (bcat[6 * n + (lane >> 4)] == (lane & 15)) ? 1.f : 0.f;
            } else {
                float d = bfloat[2 * n] - 0.1f * (float)(lane - 48);
                v0 = expf(-10.f * d * d);
            }
            if (lane < 4) { float d = bfloat[2 * n] - 0.1f * (float)(lane + 16); v1 = expf(-10.f * d * d); }
            else if (lane == 4) v1 = 1.f;
        }
        sf[wid][r][lane] = v0;
        sf[wid][r][64 + lane] = v1;
    }
    __syncthreads();
    {
        int ar = lane & 15, aq = (lane >> 4) << 3;
        #pragma unroll
        for (int s = 0; s < 3; ++s) {
            const float* src = &sf[wid][ar][s * 32 + aq];
            uint_t pk[4];
            #pragma unroll
            for (int j = 0; j < 4; ++j)
                pk[j] = (uint_t)f2bf(src[2 * j]) | ((uint_t)f2bf(src[2 * j + 1]) << 16);
            *(uint4*)(f_t + ((((size_t)blockIdx.x * 4 + wid) * 3 + s) * 64 + lane) * 8) =
                make_uint4(pk[0], pk[1], pk[2], pk[3]);
        }
    }
}

__global__ __launch_bounds__(256) void k_feat_ab(
    const int* __restrict__ rp, const int* __restrict__ peid,
    const float* __restrict__ bfloat, const int* __restrict__ bcat,
    ushort_t* __restrict__ fab_t)
{
    __shared__ float sf[4][16][132];
    int tid = threadIdx.x, wid = tid >> 6, lane = tid & 63;
    int g0 = blockIdx.x * 64 + wid * 16;
    for (int r = 0; r < 16; ++r) {
        int n = g0 + r;
        float v0 = 0.f, v1 = 0.f;
        if (n < NA) {
            int p0 = rp[n], p1 = rp[n + 1];
            for (int pb = p0; pb < p1; pb += 64) {
                int cnt = min(p1 - pb, 64);
                int cp = 0; float bv = 0.f;
                if (lane < cnt) {
                    int e = peid[pb + lane];
                    cp = (bcat[3 * e] & 15) | ((bcat[3 * e + 1] & 15) << 4) | ((bcat[3 * e + 2] & 15) << 8);
                    bv = bfloat[e];
                }
                for (int i = 0; i < cnt; ++i) {
                    int cpi = __shfl(cp, i);
                    float bvi = __shfl(bv, i);
                    if (lane < 48) {
                        v0 += (((cpi >> ((lane >> 4) << 2)) & 15) == (lane & 15)) ? 1.f : 0.f;
                    } else {
                        float d = bvi - 0.1f * (float)(lane - 48);
                        v0 += expf(-10.f * d * d);
                    }
                    if (lane < 4) { float d = bvi - 0.1f * (float)(lane + 16); v1 += expf(-10.f * d * d); }
                    else if (lane == 4) v1 += 1.f;
                }
            }
        }
        sf[wid][r][lane] = v0;
        sf[wid][r][64 + lane] = v1;
    }
    __syncthreads();
    int ar = lane & 15, aq = (lane >> 4) << 3;
    #pragma unroll
    for (int s = 0; s < 3; ++s) {
        const float* src = &sf[wid][ar][s * 32 + aq];
        uint_t pk[4];
        #pragma unroll
        for (int j = 0; j < 4; ++j)
            pk[j] = (uint_t)f2bf(src[2 * j]) | ((uint_t)f2bf(src[2 * j + 1]) << 16);
        *(uint4*)(fab_t + ((((size_t)blockIdx.x * 4 + wid) * 3 + s) * 64 + lane) * 8) =
            make_uint4(pk[0], pk[1], pk[2], pk[3]);
    }
}

// ================= weight folds (fp32) =================
__global__ __launch_bounds__(256) void k_fold(
    const float* __restrict__ ba_w1, const float* __restrict__ lbemb,
    const float* __restrict__ rwb, const float* __restrict__ rbvb,
    const float* __restrict__ rwa, const float* __restrict__ rbva,
    const float* __restrict__ ab_w1, const float* __restrict__ bei,
    const float* __restrict__ brw, const float* __restrict__ brb,
    float* __restrict__ W1ext, float* __restrict__ W1ab0x)
{
    int f = blockIdx.x * 256 + threadIdx.x;
    if (f < 262144) {
        int n = f & 255, k = (f >> 8) & 127, l = f >> 15;
        float v = 0.f;
        if (k <= 100) {
            const float* w1 = ba_w1 + (size_t)l * 32768 + n;
            if (k == 100) {
                const float* r1 = rbvb + (size_t)l * 128;
                const float* r2 = rbva + (size_t)l * 128;
                for (int c = 0; c < 128; ++c) v += (r1[c] + r2[c]) * w1[(size_t)c * 256];
            } else {
                const float* row = (k < 48) ? lbemb + ((size_t)l * 48 + k) * 128
                                 : (k < 68) ? rwb + ((size_t)l * 20 + (k - 48)) * 128
                                            : rwa + ((size_t)l * 32 + (k - 68)) * 128;
                for (int c = 0; c < 128; ++c) v += row[c] * w1[(size_t)c * 256];
            }
        }
        W1ext[f] = v;
    } else if (f < 286720) {
        int f2 = f - 262144;
        int n = f2 & 255, k = f2 >> 8;
        float v = 0.f;
        if (k <= 68) {
            const float* w1 = ab_w1 + n;
            const float* row = (k < 48) ? bei + (size_t)k * 128
                             : (k < 68) ? brw + (size_t)(k - 48) * 128
                                        : brb;
            for (int c = 0; c < 128; ++c) v += row[c] * w1[(size_t)c * 256];
        }
        W1ab0x[f2] = v;
    }
}

// ================= pack weights into B-frag order =================
// regions (frag units): [0,7168) W1ab0 K224; [7168,35840) ab_w1 l1-7;
// [35840,68608) W1ext_ba; [68608,134144) w2 ab+ba; [134144,146432) G
__global__ __launch_bounds__(256) void k_pack(
    const float* __restrict__ ab_w1, const float* __restrict__ W1ab0x,
    const float* __restrict__ W1ext, const float* __restrict__ ab_w2,
    const float* __restrict__ ba_w2, const float* __restrict__ lbemb,
    const float* __restrict__ rwb, const float* __restrict__ rbvb,
    ushort_t* __restrict__ wp)
{
    int f = blockIdx.x * 256 + threadIdx.x;
    if (f >= 146432) return;
    int lane = f & 63;
    int k0 = 0, n = 0, N = 256;
    const float* W = nullptr;
    float vals[8];
    if (f < 7168) {
        int ts = f >> 6; int s = ts % 7, t = ts / 7;
        k0 = s * 32 + ((lane >> 4) << 3); n = t * 16 + (lane & 15); N = 256;
        if (k0 < 128) W = ab_w1;
        else { W = W1ab0x; k0 -= 128; }
    } else if (f < 35840) {
        int f2 = f - 7168; int ts = f2 >> 6;
        int s = ts & 3, t = (ts >> 2) & 15, l = (ts >> 6) + 1;
        W = ab_w1 + (size_t)l * 32768; N = 256;
        k0 = s * 32 + ((lane >> 4) << 3); n = t * 16 + (lane & 15);
    } else if (f < 68608) {
        int f2 = f - 35840; int ts = f2 >> 6;
        int s = ts & 3, t = (ts >> 2) & 15, l = ts >> 6;
        W = W1ext + (size_t)l * 32768; N = 256;
        k0 = s * 32 + ((lane >> 4) << 3); n = t * 16 + (lane & 15);
    } else if (f < 134144) {
        int f2 = f - 68608; int ts = f2 >> 6;
        int s = ts & 7, t = (ts >> 3) & 7, l = (ts >> 6) & 7, grp = ts >> 9;
        W = (grp ? ba_w2 : ab_w2) + (size_t)l * 32768; N = 128;
        k0 = s * 32 + ((lane >> 4) << 3); n = t * 16 + (lane & 15);
    } else {
        int f2 = f - 134144; int ts = f2 >> 6;
        int s = ts % 3, t = (ts / 3) & 7, l = ts / 24;
        N = 128; k0 = s * 32 + ((lane >> 4) << 3); n = t * 16 + (lane & 15);
        #pragma unroll
        for (int j = 0; j < 8; ++j) {
            int k = k0 + j; float v;
            if (k < 48) v = lbemb[(size_t)l * 6144 + (size_t)k * 128 + n];
            else if (k < 68) v = rwb[(size_t)l * 2560 + (size_t)(k - 48) * 128 + n];
            else if (k == 68) v = rbvb[(size_t)l * 128 + n];
            else v = 0.f;
            vals[j] = v;
        }
    }
    if (W) {
        #pragma unroll
        for (int j = 0; j < 8; ++j) vals[j] = W[(size_t)(k0 + j) * N + n];
    }
    uint_t pk[4];
    #pragma unroll
    for (int j = 0; j < 4; ++j)
        pk[j] = (uint_t)f2bf(vals[2 * j]) | ((uint_t)f2bf(vals[2 * j + 1]) << 16);
    *(uint4*)(wp + (size_t)f * 8) = make_uint4(pk[0], pk[1], pk[2], pk[3]);
}

// ================= batched ba MLP: round-5 k_mlp_ba body, layer from blockIdx&3 =================
__global__ __launch_bounds__(256) void k_ba_batch(
    const ushort_t* __restrict__ aext_t, const ushort_t* __restrict__ f_t,
    const ushort_t* __restrict__ wp,
    const float* __restrict__ ba_b1, const float* __restrict__ ba_b2,
    const float* __restrict__ ba_g, const float* __restrict__ ba_bt,
    ushort_t* __restrict__ pool, float* __restrict__ edge_out,
    int lbase, float inv_sqrt_n)
{
    __shared__ ushort_t sC1[4][16 * 264];
    int tid = threadIdx.x, wid = tid >> 6, lane = tid & 63;
    int l = lbase + (blockIdx.x & 3);
    int rb = blockIdx.x >> 2;
    const ushort_t* w1p = wp + ((size_t)35840 + (size_t)l * 4096) * 8;
    const ushort_t* w2p = wp + ((size_t)68608 + (size_t)(8 + l) * 4096) * 8;
    const ushort_t* gp  = wp + ((size_t)134144 + (size_t)l * 1536) * 8;
    const float* b1 = ba_b1 + l * HH;
    const float* b2 = ba_b2 + l * DD;
    const float* g  = ba_g + l * DD;
    const float* bt = ba_bt + l * DD;
    ushort_t* outb = pool + (size_t)(l & 3) * NHALF * DD;

    int arow = lane & 15, aq = (lane >> 4) << 3;

    s16x8 af[4];
    #pragma unroll
    for (int s = 0; s < 4; ++s)
        af[s] = *(const s16x8*)(aext_t + ((((size_t)rb * 4 + wid) * 4 + s) * 64 + lane) * 8);

    for (int t = 0; t < 16; ++t) {
        f32x4 acc = {0.f, 0.f, 0.f, 0.f};
        #pragma unroll
        for (int s = 0; s < 4; ++s) {
            s16x8 bf = *(const s16x8*)(w1p + ((size_t)(t * 4 + s) * 64 + lane) * 8);
            acc = __builtin_amdgcn_mfma_f32_16x16x32_bf16(af[s], bf, acc, 0, 0, 0);
        }
        int n = t * 16 + (lane & 15);
        float b1v = b1[n];
        int r0 = (lane >> 4) << 2;
        #pragma unroll
        for (int r = 0; r < 4; ++r)
            sC1[wid][(r0 + r) * 264 + n] = f2bf(fmaxf(acc[r] + b1v, 0.f));
    }
    __syncthreads();

    s16x8 a2[8];
    #pragma unroll
    for (int s = 0; s < 8; ++s) a2[s] = *(const s16x8*)&sC1[wid][arow * 264 + s * 32 + aq];
    f32x4 c2[8];
    for (int t = 0; t < 8; ++t) {
        f32x4 acc = {0.f, 0.f, 0.f, 0.f};
        #pragma unroll
        for (int s = 0; s < 8; ++s) {
            s16x8 bf = *(const s16x8*)(w2p + ((size_t)(t * 8 + s) * 64 + lane) * 8);
            acc = __builtin_amdgcn_mfma_f32_16x16x32_bf16(a2[s], bf, acc, 0, 0, 0);
        }
        c2[t] = acc;
    }

    s16x8 af3[3];
    #pragma unroll
    for (int s = 0; s < 3; ++s)
        af3[s] = *(const s16x8*)(f_t + ((((size_t)rb * 4 + wid) * 3 + s) * 64 + lane) * 8);

    int colb = lane & 15;
    {
        float b2v[8];
        #pragma unroll
        for (int t = 0; t < 8; ++t) b2v[t] = b2[t * 16 + colb];
        #pragma unroll
        for (int t = 0; t < 8; ++t)
            #pragma unroll
            for (int r = 0; r < 4; ++r) c2[t][r] += b2v[t];
    }
    float mu4[4], rs4[4];
    #pragma unroll
    for (int r = 0; r < 4; ++r) {
        float s = 0.f, ss = 0.f;
        #pragma unroll
        for (int t = 0; t < 8; ++t) { float x = c2[t][r]; s += x; ss += x * x; }
        #pragma unroll
        for (int m = 1; m < 16; m <<= 1) {
            s  += __shfl_xor(s, m);
            ss += __shfl_xor(ss, m);
        }
        float mu = s * (1.f / 128.f);
        float var = ss * (1.f / 128.f) - mu * mu;
        mu4[r] = mu;
        rs4[r] = rsqrtf(var + 1e-5f);
    }
    int r0 = (lane >> 4) << 2;
    int growb = rb * 64 + wid * 16 + r0;
    #pragma unroll
    for (int t = 0; t < 8; ++t) {
        f32x4 racc = {0.f, 0.f, 0.f, 0.f};
        #pragma unroll
        for (int s = 0; s < 3; ++s) {
            s16x8 bf = *(const s16x8*)(gp + ((size_t)(t * 3 + s) * 64 + lane) * 8);
            racc = __builtin_amdgcn_mfma_f32_16x16x32_bf16(af3[s], bf, racc, 0, 0, 0);
        }
        int n = t * 16 + colb;
        float gv = g[n], btv = bt[n];
        #pragma unroll
        for (int r = 0; r < 4; ++r) {
            int grow = growb + r;
            if (grow < NHALF) {
                float y = (c2[t][r] - mu4[r]) * rs4[r] * gv + btv;
                float o = fmaxf(y * inv_sqrt_n, 0.f) + racc[r];
                if (l < 7) {
                    outb[(size_t)grow * DD + n] = f2bf(o);
                } else {
                    edge_out[(size_t)(2 * grow) * DD + n] = o;
                    edge_out[(size_t)(2 * grow + 1) * DD + n] = o;
                }
            }
        }
    }
}

// ================= fused gather + MLP (ab path) — round-5 verbatim =================
template<int KS, bool L0>
__global__ __launch_bounds__(256) void k_mlp_ab(
    const uint_t* __restrict__ node2, const uint_t* __restrict__ half2,
    const ushort_t* __restrict__ fab_t,
    const int* __restrict__ rp, const int* __restrict__ psrc,
    const int* __restrict__ peid,
    const ushort_t* __restrict__ w1p, const float* __restrict__ b1,
    const ushort_t* __restrict__ w2p, const float* __restrict__ b2,
    const float* __restrict__ g, const float* __restrict__ bt,
    const float* __restrict__ resid, float* __restrict__ outf,
    ushort_t* __restrict__ outb, float inv_sqrt_n)
{
    __shared__ ushort_t sA[4][16 * 136];
    __shared__ ushort_t sC1[4][16 * 264];
    int tid = threadIdx.x, wid = tid >> 6, lane = tid & 63;
    int g0 = blockIdx.x * 64 + wid * 16;

    for (int r = 0; r < 16; ++r) {
        int n = g0 + r;
        float v0 = 0.f, v1 = 0.f;
        if (n < NA) {
            int p0 = rp[n], p1 = rp[n + 1];
            for (int p = p0; p < p1; ++p) {
                int s = psrc[p];
                uint_t a = node2[(size_t)s * 64 + lane];
                v0 += bf2f((ushort_t)(a & 0xffff));
                v1 += bf2f((ushort_t)(a >> 16));
                if (!L0) {
                    int e = peid[p];
                    uint_t b = half2[(size_t)(e >> 1) * 64 + lane];
                    v0 += bf2f((ushort_t)(b & 0xffff));
                    v1 += bf2f((ushort_t)(b >> 16));
                }
            }
        }
        *(uint_t*)&sA[wid][r * 136 + lane * 2] = (uint_t)f2bf(v0) | ((uint_t)f2bf(v1) << 16);
    }
    __syncthreads();

    int arow = lane & 15, aq = (lane >> 4) << 3;
    s16x8 af[KS];
    #pragma unroll
    for (int s = 0; s < 4; ++s) af[s] = *(const s16x8*)&sA[wid][arow * 136 + s * 32 + aq];
    if (L0) {
        #pragma unroll
        for (int s = 0; s < 3; ++s)
            af[4 + s] = *(const s16x8*)(fab_t + ((((size_t)blockIdx.x * 4 + wid) * 3 + s) * 64 + lane) * 8);
    }

    for (int t = 0; t < 16; ++t) {
        f32x4 acc = {0.f, 0.f, 0.f, 0.f};
        #pragma unroll
        for (int s = 0; s < KS; ++s) {
            s16x8 bf = *(const s16x8*)(w1p + ((size_t)(t * KS + s) * 64 + lane) * 8);
            acc = __builtin_amdgcn_mfma_f32_16x16x32_bf16(af[s], bf, acc, 0, 0, 0);
        }
        int n = t * 16 + (lane & 15);
        float b1v = b1[n];
        int r0 = (lane >> 4) << 2;
        #pragma unroll
        for (int r = 0; r < 4; ++r)
            sC1[wid][(r0 + r) * 264 + n] = f2bf(fmaxf(acc[r] + b1v, 0.f));
    }
    __syncthreads();

    s16x8 a2[8];
    #pragma unroll
    for (int s = 0; s < 8; ++s) a2[s] = *(const s16x8*)&sC1[wid][arow * 264 + s * 32 + aq];
    f32x4 c2[8];
    for (int t = 0; t < 8; ++t) {
        f32x4 acc = {0.f, 0.f, 0.f, 0.f};
        #pragma unroll
        for (int s = 0; s < 8; ++s) {
            s16x8 bf = *(const s16x8*)(w2p + ((size_t)(t * 8 + s) * 64 + lane) * 8);
            acc = __builtin_amdgcn_mfma_f32_16x16x32_bf16(a2[s], bf, acc, 0, 0, 0);
        }
        c2[t] = acc;
    }

    int colb = lane & 15;
    float b2v[8], gv[8], btv[8];
    #pragma unroll
    for (int t = 0; t < 8; ++t) {
        int n = t * 16 + colb;
        b2v[t] = b2[n]; gv[t] = g[n]; btv[t] = bt[n];
    }
    #pragma unroll
    for (int t = 0; t < 8; ++t)
        #pragma unroll
        for (int r = 0; r < 4; ++r) c2[t][r] += b2v[t];

    int r0 = (lane >> 4) << 2;
    #pragma unroll
    for (int r = 0; r < 4; ++r) {
        float s = 0.f, ss = 0.f;
        #pragma unroll
        for (int t = 0; t < 8; ++t) { float x = c2[t][r]; s += x; ss += x * x; }
        #pragma unroll
        for (int m = 1; m < 16; m <<= 1) {
            s  += __shfl_xor(s, m);
            ss += __shfl_xor(ss, m);
        }
        float mu = s * (1.f / 128.f);
        float var = ss * (1.f / 128.f) - mu * mu;
        float rstd = rsqrtf(var + 1e-5f);
        int grow = g0 + r0 + r;
        if (grow < NA) {
            #pragma unroll
            for (int t = 0; t < 8; ++t) {
                int n = t * 16 + colb;
                float y = (c2[t][r] - mu) * rstd * gv[t] + btv[t];
                float o = fmaxf(y * inv_sqrt_n, 0.f) + resid[(size_t)grow * DD + n];
                outf[(size_t)grow * DD + n] = o;
                outb[(size_t)grow * DD + n] = f2bf(o);
            }
        }
    }
}

// ---------------- graph = node.mean(axis=0)
__global__ __launch_bounds__(256) void k_graph_mean(
    const float* __restrict__ node, float* __restrict__ graph)
{
    int tid = threadIdx.x;
    int c = tid & 127, h = tid >> 7;
    const int rpb = 250;
    int r0 = blockIdx.x * rpb;
    float s = 0.f;
    for (int r = r0 + h; r < r0 + rpb; r += 2) s += node[(size_t)r * DD + c];
    __shared__ float sS[256];
    sS[tid] = s;
    __syncthreads();
    if (tid < 128) atomicAdd(&graph[c], (sS[tid] + sS[tid + 128]) * (1.f / 30000.f));
}

extern "C" void kernel_launch(void* const* d_in, const int* in_sizes, int n_in,
                              void* d_out, int out_size, void* d_ws, size_t ws_size,
                              hipStream_t stream)
{
    const int*   atom_cat         = (const int*)d_in[0];
    const int*   bond_cat         = (const int*)d_in[1];
    const float* bond_float       = (const float*)d_in[2];
    const float* angle_float      = (const float*)d_in[3];
    const int*   ab_src           = (const int*)d_in[4];
    const int*   ab_dst           = (const int*)d_in[5];
    const int*   ba_src           = (const int*)d_in[6];
    const int*   ba_dst           = (const int*)d_in[7];
    const float* atom_emb         = (const float*)d_in[8];
    const float* bond_emb_init    = (const float*)d_in[9];
    const float* bond_rbf_w_init  = (const float*)d_in[10];
    const float* bond_rbf_b_init  = (const float*)d_in[11];
    const float* layer_bond_emb   = (const float*)d_in[12];
    const float* layer_bond_rbf_w = (const float*)d_in[13];
    const float* layer_bond_rbf_b = (const float*)d_in[14];
    const float* layer_angle_rbf_w= (const float*)d_in[15];
    const float* layer_angle_rbf_b= (const float*)d_in[16];
    const float* ab_w1 = (const float*)d_in[17];
    const float* ab_b1 = (const float*)d_in[18];
    const float* ab_w2 = (const float*)d_in[19];
    const float* ab_b2 = (const float*)d_in[20];
    const float* ab_g  = (const float*)d_in[21];
    const float* ab_bt = (const float*)d_in[22];
    const float* ba_w1 = (const float*)d_in[23];
    const float* ba_b1 = (const float*)d_in[24];
    const float* ba_w2 = (const float*)d_in[25];
    const float* ba_b2 = (const float*)d_in[26];
    const float* ba_g  = (const float*)d_in[27];
    const float* ba_bt = (const float*)d_in[28];

    float* node     = (float*)d_out;
    float* edge_out = node + (size_t)NA * DD;
    float* graph    = edge_out + (size_t)NB * DD;

    // ---- ws layout (round-5 layout; half_bf replaced by 4-slot pool)
    ushort_t* nbf0   = (ushort_t*)d_ws;                        // NA*128
    ushort_t* nbf1   = nbf0 + (size_t)NA * DD;                 // NA*128
    ushort_t* pool   = nbf1 + (size_t)NA * DD;                 // 4*NHALF*128
    ushort_t* aext_t = pool + (size_t)4 * NHALF * DD;          // 782*8192
    ushort_t* f_t    = aext_t + (size_t)782 * 8192;            // 782*6144
    ushort_t* fab_t  = f_t + (size_t)782 * 6144;               // 469*6144
    ushort_t* wp     = fab_t + (size_t)469 * 6144;             // 146432*8
    float*    W1ext  = (float*)(wp + (size_t)146432 * 8);      // 262144
    float*    W1ab0x = W1ext + 262144;                         // 24576
    int*      cur_ab = (int*)(W1ab0x + 24576);                 // NA
    int*      cur_ba = cur_ab + NA;                            // NHALF
    int*      rp_ab  = cur_ba + NHALF;                         // NA+1
    int*      rp_ba  = rp_ab + NA + 1;                         // NHALF+1
    int*      psrc_ab= rp_ba + NHALF + 1;                      // NB
    int*      peid_ab= psrc_ab + NB;                           // NB
    int*      psrc_ba= peid_ab + NB;                           // NANG
    float*    pang   = (float*)(psrc_ba + NANG);               // NANG

    const float isn_a = (float)(1.0 / sqrt(30000.0));
    const float isn_h = (float)(1.0 / sqrt(50000.0));

    // ---- CSR build
    hipMemsetAsync(cur_ab, 0, (size_t)(NA + NHALF) * sizeof(int), stream);
    k_hist2<<<(NB + NANG + 255) / 256, 256, 0, stream>>>(ab_dst, cur_ab, ba_dst, cur_ba);
    k_scan<<<2, 1024, 0, stream>>>(cur_ab, rp_ab, cur_ba, rp_ba);
    k_fill_ab<<<(NB + 255) / 256, 256, 0, stream>>>(ab_src, ab_dst, cur_ab, psrc_ab, peid_ab);
    k_fill_ba<<<(NANG + 255) / 256, 256, 0, stream>>>(ba_src, ba_dst, angle_float, cur_ba, psrc_ba, pang);

    // ---- features + folds + packing
    k_feat_ba<<<782, 256, 0, stream>>>(rp_ba, psrc_ba, pang, bond_float, bond_cat, aext_t, f_t);
    k_feat_ab<<<469, 256, 0, stream>>>(rp_ab, peid_ab, bond_float, bond_cat, fab_t);
    k_fold<<<1120, 256, 0, stream>>>(ba_w1, layer_bond_emb, layer_bond_rbf_w,
        layer_bond_rbf_b, layer_angle_rbf_w, layer_angle_rbf_b,
        ab_w1, bond_emb_init, bond_rbf_w_init, bond_rbf_b_init, W1ext, W1ab0x);
    k_pack<<<572, 256, 0, stream>>>(ab_w1, W1ab0x, W1ext, ab_w2, ba_w2,
        layer_bond_emb, layer_bond_rbf_w, layer_bond_rbf_b, wp);

    k_node_init<<<NA / 2, 256, 0, stream>>>(atom_cat, atom_emb, node, nbf0);

    // ---- batched ba layers 0-3 -> pool[0..3]
    k_ba_batch<<<782 * 4, 256, 0, stream>>>(aext_t, f_t, wp, ba_b1, ba_b2, ba_g, ba_bt,
        pool, edge_out, 0, isn_h);

    ushort_t* nbf[2] = {nbf0, nbf1};
    for (int l = 0; l < LL; ++l) {
        const uint_t* rd = (const uint_t*)nbf[l & 1];
        ushort_t* wr = nbf[1 - (l & 1)];
        const uint_t* halfbuf = (const uint_t*)(pool + (size_t)((l - 1) & 3) * NHALF * DD);
        const ushort_t* ab_w1p = l ? wp + ((size_t)7168 + (size_t)(l - 1) * 4096) * 8 : wp;
        const ushort_t* ab_w2p = wp + ((size_t)68608 + (size_t)l * 4096) * 8;

        if (l == 0)
            k_mlp_ab<7, true><<<469, 256, 0, stream>>>(
                rd, rd, fab_t, rp_ab, psrc_ab, peid_ab,
                ab_w1p, ab_b1, ab_w2p, ab_b2, ab_g, ab_bt,
                node, node, wr, isn_a);
        else
            k_mlp_ab<4, false><<<469, 256, 0, stream>>>(
                rd, halfbuf, fab_t, rp_ab, psrc_ab, peid_ab,
                ab_w1p, ab_b1 + l * HH, ab_w2p, ab_b2 + l * DD,
                ab_g + l * DD, ab_bt + l * DD, node, node, wr, isn_a);

        if (l == 3)   // pool[0..2] consumed; refill with layers 4-6 (+edge from 7)
            k_ba_batch<<<782 * 4, 256, 0, stream>>>(aext_t, f_t, wp, ba_b1, ba_b2, ba_g, ba_bt,
                pool, edge_out, 4, isn_h);
    }

    hipMemsetAsync(graph, 0, DD * sizeof(float), stream);
    k_graph_mean<<<120, 256, 0, stream>>>(node, graph);
}